// Round 8
// baseline (849.595 us; speedup 1.0000x reference)
//
#include <hip/hip_runtime.h>
#include <math.h>

#define B_ 32
#define T_ 1024
#define F_ 64
#define H_ 128
#define D_ 192
#define KH_ 16
#define C1_ 128
#define C2_ 256
#define C3_ 128
#define NC_ 10

typedef float v2f __attribute__((ext_vector_type(2)));
typedef float f32x4 __attribute__((ext_vector_type(4)));
typedef __bf16 bfrag __attribute__((ext_vector_type(8)));

__device__ __forceinline__ float sig_(float x){ return 1.f/(1.f+__expf(-x)); }
__device__ __forceinline__ float tanh_(float x){ return 1.f - 2.f/(__expf(2.f*x)+1.f); }
__device__ __forceinline__ float gelu_(float x){ return 0.5f*x*(1.f+erff(x*0.70710678118654752f)); }
__device__ __forceinline__ float softplus_(float x){ return fmaxf(x,0.f) + log1pf(__expf(-fabsf(x))); }

__device__ __forceinline__ unsigned bfpack(float a, float b){
  unsigned ua = __float_as_uint(a), ub = __float_as_uint(b);
  ua = ua + 0x7FFFu + ((ua>>16)&1u);
  ub = ub + 0x7FFFu + ((ub>>16)&1u);
  return (ua>>16) | (ub & 0xFFFF0000u);
}
__device__ __forceinline__ unsigned short bf1(float a){
  unsigned ua = __float_as_uint(a);
  ua = ua + 0x7FFFu + ((ua>>16)&1u);
  return (unsigned short)(ua>>16);
}
__device__ __forceinline__ float bf2f(unsigned short h){
  return __uint_as_float(((unsigned)h)<<16);
}

#define QPERM_XOR1(x) __int_as_float(__builtin_amdgcn_mov_dpp(__float_as_int(x), 0xB1, 0xF, 0xF, true))
#define QPERM_XOR2(x) __int_as_float(__builtin_amdgcn_mov_dpp(__float_as_int(x), 0x4E, 0xF, 0xF, true))

#define LDS_BARRIER() asm volatile("s_waitcnt lgkmcnt(0)\n\ts_barrier" ::: "memory")

// ================================================================ bodies

// ---- ax precompute (transposed out: axT[b][j][t])
__device__ __forceinline__ void ax_body(int blk, char* smemraw,
    const float* __restrict__ x, const float* __restrict__ w1, const float* __restrict__ b1,
    float* __restrict__ axT)
{
  struct AxS { float xs[16][68]; float w1s[64][16]; };
  AxS* sm = (AxS*)smemraw;
  const int bt0 = blk*16;
  const int tid = threadIdx.x;
  for(int i=tid;i<64*16;i+=256){ sm->w1s[i>>4][i&15] = w1[i]; }
  for(int i=tid;i<16*64;i+=256){ const int r=i>>6, d=i&63; sm->xs[r][d] = x[(size_t)(bt0+r)*64 + d]; }
  __syncthreads();
  const int r = tid>>4, j = tid&15;
  float s = b1[j];
  #pragma unroll
  for(int d=0; d<64; d++) s += sm->xs[r][d]*sm->w1s[d][j];
  const int bt = bt0 + r;
  axT[((size_t)(bt>>10)*16 + j)*1024 + (bt&1023)] = s;
}

// ---- weight prepack (bf16 MFMA B-fragment blocks, all 3 convs)
__device__ __forceinline__ void prepack_body(int blk,
    const float* __restrict__ w1s, const float* __restrict__ w2s, const float* __restrict__ w3s,
    unsigned short* __restrict__ wp1, unsigned short* __restrict__ wp2, unsigned short* __restrict__ wp3)
{
  int e = blk*256 + threadIdx.x;
  if(e >= 65536+163840+98304) return;
  const float* w; unsigned short* wp; int Cout, Cin, Kw;
  if(e < 65536){ w=w1s; wp=wp1; Cout=C1_; Cin=F_;  Kw=8; }
  else if(e < 65536+163840){ e-=65536; w=w2s; wp=wp2; Cout=C2_; Cin=C1_; Kw=5; }
  else { e-=229376; w=w3s; wp=wp3; Cout=C3_; Cin=C2_; Kw=3; }
  const int co = e/(Cin*Kw);
  const int rem = e - co*(Cin*Kw);
  const int ci = rem/Kw, kw = rem - ci*Kw;
  const int off = (((ci>>5)*Kw + kw)*(Cout>>4) + (co>>4))*512 + ((co&15)*4 + ((ci>>3)&3))*8 + (ci&7);
  wp[off] = bf1(w[e]);
}

// ---- row norms for 8 rows starting at rowbase; writes bf16 hi/lo split
__device__ __forceinline__ void norm8_body(size_t rowbase,
    const float* __restrict__ hidden,
    unsigned short* __restrict__ hnhi, unsigned short* __restrict__ hnlo)
{
  const size_t row = rowbase + (threadIdx.x>>5);
  const int l = threadIdx.x&31;
  const float* hr = hidden + row*H_;
  float s = 0.f;
  for(int k=l;k<H_;k+=32){ float v=hr[k]; s+=v*v; }
  #pragma unroll
  for(int m=16;m>=1;m>>=1) s += __shfl_xor(s, m, 64);
  const float inv = 1.f/fmaxf(sqrtf(s), 1e-8f);
  const float4 v = *(const float4*)&hr[l*4];
  const float f0=v.x*inv, f1=v.y*inv, f2=v.z*inv, f3=v.w*inv;
  const unsigned short h0=bf1(f0), h1=bf1(f1), h2=bf1(f2), h3=bf1(f3);
  uint2 phi; phi.x = (unsigned)h0 | ((unsigned)h1<<16); phi.y = (unsigned)h2 | ((unsigned)h3<<16);
  *(uint2*)&hnhi[row*H_ + l*4] = phi;
  const unsigned short g0=bf1(f0-bf2f(h0)), g1=bf1(f1-bf2f(h1)), g2=bf1(f2-bf2f(h2)), g3=bf1(f3-bf2f(h3));
  uint2 plo; plo.x = (unsigned)g0 | ((unsigned)g1<<16); plo.y = (unsigned)g2 | ((unsigned)g3<<16);
  *(uint2*)&hnlo[row*H_ + l*4] = plo;
}

// ---- S-Gram TILE: one (b, i0-block, j0-block) 64x64 tile via bf16 MFMA,
// hi/lo split. No LDS: A/B fragments load directly from L2-resident hn
// (the old LDS stride 136 was only bank padding; fragment<->row/col mapping
// is identical with stride H). Reduce partials over m via shfl, accumulate
// into rowsum/psum with native f64 atomics. 16x finer than the old s_body
// -> high occupancy (no 78KB LDS -> was 2 blocks/CU, one residency wave),
// and tiles become schedulable into lstm-segment shadows by dispatch order.
__device__ __forceinline__ void stile_body(int b, int i0, int j0,
    const unsigned short* __restrict__ hnhi, const unsigned short* __restrict__ hnlo,
    double* __restrict__ rowsum, double* __restrict__ psum)
{
  const int tid = threadIdx.x, l = tid & 63, wv = tid >> 6;
  const int m = l & 15, q = l >> 4;
  const size_t arow = ((size_t)b*T_ + i0 + wv*16 + m)*H_;

  f32x4 acc[4];
  #pragma unroll
  for(int nt=0;nt<4;nt++) acc[nt] = (f32x4)(0.f);
  #pragma unroll
  for(int kc=0;kc<4;kc++){
    const bfrag Ah = *(const bfrag*)&hnhi[arow + kc*32 + q*8];
    const bfrag Al = *(const bfrag*)&hnlo[arow + kc*32 + q*8];
    #pragma unroll
    for(int nt=0;nt<4;nt++){
      const size_t brow = ((size_t)b*T_ + j0 + nt*16 + m)*H_ + kc*32 + q*8;
      const bfrag Bh = *(const bfrag*)&hnhi[brow];
      const bfrag Bl = *(const bfrag*)&hnlo[brow];
      acc[nt] = __builtin_amdgcn_mfma_f32_16x16x32_bf16(Ah, Bh, acc[nt], 0, 0, 0);
      acc[nt] = __builtin_amdgcn_mfma_f32_16x16x32_bf16(Al, Bh, acc[nt], 0, 0, 0);
      acc[nt] = __builtin_amdgcn_mfma_f32_16x16x32_bf16(Ah, Bl, acc[nt], 0, 0, 0);
    }
  }
  double rs[4]={0,0,0,0}, ps[4]={0,0,0,0};
  #pragma unroll
  for(int nt=0;nt<4;nt++){
    const int gj = j0 + nt*16 + m;
    #pragma unroll
    for(int r=0;r<4;r++){
      const int gi = i0 + wv*16 + q*4 + r;
      if(gi == gj) continue;
      const float sv = __expf(-5.5f*(1.f - acc[nt][r]));
      rs[r] += (double)sv;
      if(gj < gi) ps[r] += (double)sv;
    }
  }
  // sum over m (lane bits 0-3)
  #pragma unroll
  for(int r=0;r<4;r++){
    #pragma unroll
    for(int mk=1;mk<16;mk<<=1){
      rs[r] += __shfl_xor(rs[r], mk, 64);
      ps[r] += __shfl_xor(ps[r], mk, 64);
    }
  }
  if(m == 0){
    const size_t gbase = (size_t)b*T_ + i0 + wv*16 + q*4;
    #pragma unroll
    for(int r=0;r<4;r++){
      unsafeAtomicAdd(&rowsum[gbase + r], rs[r]);
      unsafeAtomicAdd(&psum[gbase + r], ps[r]);
    }
  }
}

// ---- cluster: prefix+dist+argmax+corr
struct CS {
  double sr[256]; double sp[256]; double bd[256]; double totR;
  float c2[2][128]; int bidx[256]; int cut;
};
__device__ __forceinline__ void cluster_body(int b, char* smemraw,
    const double* __restrict__ rowsum, const double* __restrict__ psum,
    const float* __restrict__ hidden, float* __restrict__ corr, int* __restrict__ cuts)
{
  CS* sm = (CS*)smemraw;
  const int tid = threadIdx.x;
  const double* r = rowsum + (size_t)b*T_;
  const double* p = psum + (size_t)b*T_;
  double r4[4], p4[4];
  #pragma unroll
  for(int q=0;q<4;q++){ r4[q]=r[tid*4+q]; p4[q]=p[tid*4+q]; }
  sm->sr[tid]=r4[0]+r4[1]+r4[2]+r4[3];
  sm->sp[tid]=p4[0]+p4[1]+p4[2]+p4[3];
  __syncthreads();
  if(tid==0){
    double ar=0, ap=0;
    for(int i=0;i<256;i++){ double tr=sm->sr[i], tp=sm->sp[i]; sm->sr[i]=ar; sm->sp[i]=ap; ar+=tr; ap+=tp; }
    sm->totR = ar;
  }
  __syncthreads();
  double cr = sm->sr[tid], cp = sm->sp[tid];
  const double full = sm->totR;
  double best = -1e308; int bi = 1;
  #pragma unroll
  for(int q=0;q<4;q++){
    cr += r4[q]; cp += p4[q];
    const int i = 4*tid + q + 1;
    if(i < T_){
      const double TL = 2.0*cp;
      const double TRv = cr - TL;
      const double BR = full - TL - 2.0*TRv;
      const double di = (double)i, dn = (double)(T_-i);
      const double dist = TL/(di*di) + BR/(dn*dn) - (2.0*TRv)/(di*dn);
      if(dist > best){ best=dist; bi=i; }
    }
  }
  sm->bd[tid]=best; sm->bidx[tid]=bi;
  __syncthreads();
  if(tid==0){
    double bb=-1e308; int ii=1;
    for(int q=0;q<256;q++){ if(sm->bd[q]>bb){ bb=sm->bd[q]; ii=sm->bidx[q]; } }
    sm->cut=ii; cuts[b]=ii;
  }
  __syncthreads();
  const int cut = sm->cut;
  const int h = tid&127, half = tid>>7;
  float s=0.f;
  const float* hb = hidden + (size_t)b*T_*H_;
  #pragma unroll 4
  for(int t=half; t<cut; t+=2) s += hb[(size_t)t*H_ + h];
  sm->c2[half][h]=s;
  __syncthreads();
  if(tid<128) corr[b*H_+tid] = (sm->c2[0][tid]+sm->c2[1][tid])/(float)cut;
}

// ---- VAE head1 (first 128 threads work)
__device__ __forceinline__ void head1_body(int b, char* smemraw,
    const float* __restrict__ corr, const float* __restrict__ hidden,
    const float* __restrict__ eps_z, const float* __restrict__ eps_cat,
    const float* __restrict__ mu_w, const float* __restrict__ mu_b,
    const float* __restrict__ std_w, const float* __restrict__ std_b,
    const float* __restrict__ muc_w, const float* __restrict__ muc_b,
    const float* __restrict__ stdc_w, const float* __restrict__ stdc_b,
    float* __restrict__ out_mu, float* __restrict__ out_std,
    float* __restrict__ out_muc, float* __restrict__ out_stdc, float* __restrict__ x1)
{
  struct H1 { float cs[128]; float xz[256]; };
  H1* sm = (H1*)smemraw;
  const int h = threadIdx.x;
  if(h<128){
    sm->cs[h]=corr[b*H_+h];
    sm->xz[h]=hidden[((size_t)b*T_ + (T_-1))*H_ + h];
  }
  __syncthreads();
  if(h<128){
    float m=mu_b[h], sdv=std_b[h];
    for(int k=0;k<H_;k++){ const float cv=sm->cs[k]; m+=cv*mu_w[k*H_+h]; sdv+=cv*std_w[k*H_+h]; }
    const float stdv = softplus_(sdv);
    out_mu[b*H_+h]=m; out_std[b*H_+h]=stdv;
    sm->xz[128+h] = m + stdv*eps_z[b*H_+h];
  }
  __syncthreads();
  if(h<128){
    float mc=muc_b[h], sc=stdc_b[h];
    for(int k=0;k<256;k++){ const float v=sm->xz[k]; mc+=v*muc_w[k*H_+h]; sc+=v*stdc_w[k*H_+h]; }
    const float stdc = softplus_(sc);
    out_muc[b*H_+h]=mc; out_stdc[b*H_+h]=stdc;
    x1[b*H_+h]=mc + stdc*eps_cat[b*H_+h];
  }
}

// ---- causal conv via bf16 MFMA + fused BN partials + optional inline SE scale
struct ConvS {
  float sescale[256];
  float seh[16];
  unsigned short xs[72*40];   // bf16 staging; reused as float part[]/ms[]
};
__device__ __forceinline__ void conv_body(int bx, int by, int bz, char* smemraw,
    const float* __restrict__ in, const unsigned short* __restrict__ wp,
    const float* __restrict__ bias,
    const float* __restrict__ se_in, const float* __restrict__ se_w1,
    const float* __restrict__ se_w2, int seR,
    float* __restrict__ y, float* __restrict__ bnacc, int Cin, int Cout, int Kw)
{
  ConvS* sm = (ConvS*)smemraw;
  unsigned short* xs = sm->xs;
  const int b = bz, t0 = bx*64, co0 = by*64;
  const int tid = threadIdx.x, l = tid&63, wv = tid>>6;
  const int q = l>>4, m = l&15;
  const int TW = 64 + Kw - 1;
  const int abase = (wv*16 + m)*40 + q*8;
  const int boff = (m*4 + q)*8;
  const bool use_se = (se_in != nullptr);

  if(use_se){
    float* ms = (float*)xs;
    if(tid<Cin) ms[tid] = se_in[b*Cin+tid] * (1.f/(float)T_);
    __syncthreads();
    if(tid<seR){ float s=0.f; for(int k=0;k<Cin;k++) s += ms[k]*se_w1[k*seR+tid]; sm->seh[tid]=fmaxf(s,0.f); }
    __syncthreads();
    if(tid<Cin){ float s=0.f; for(int k=0;k<seR;k++) s += sm->seh[k]*se_w2[k*Cin+tid]; sm->sescale[tid]=sig_(s); }
  }

  f32x4 acc[4];
  #pragma unroll
  for(int nt=0;nt<4;nt++) acc[nt] = (f32x4)(0.f);

  const int nchunks = Cin >> 5;
  for(int cc=0; cc<nchunks; cc++){
    __syncthreads();
    for(int idx=tid; idx<TW*8; idx+=256){
      const int r = idx>>3, c4 = (idx&7)*4;
      const int tg = t0 - (Kw-1) + r;
      uint2 pk = make_uint2(0u, 0u);
      if(tg >= 0){
        float4 v = *(const float4*)&in[((size_t)b*T_ + tg)*Cin + cc*32 + c4];
        if(use_se){
          const float4 s4 = *(const float4*)&sm->sescale[cc*32 + c4];
          v.x*=s4.x; v.y*=s4.y; v.z*=s4.z; v.w*=s4.w;
        }
        pk.x = bfpack(v.x, v.y); pk.y = bfpack(v.z, v.w);
      }
      *(uint2*)&xs[r*40 + c4] = pk;
    }
    __syncthreads();
    for(int kw=0; kw<Kw; kw++){
      const bfrag Af = *(const bfrag*)&xs[abase + kw*40];
      #pragma unroll
      for(int nt=0; nt<4; nt++){
        const unsigned short* wpp = wp + ((size_t)((cc*Kw + kw)*(Cout>>4) + (by*4 + nt)))*512 + boff;
        const bfrag Bf = *(const bfrag*)wpp;
        acc[nt] = __builtin_amdgcn_mfma_f32_16x16x32_bf16(Af, Bf, acc[nt], 0, 0, 0);
      }
    }
  }
  __syncthreads();
  float* part = (float*)xs;
  const int t_base = t0 + wv*16 + q*4;
  #pragma unroll
  for(int nt=0; nt<4; nt++){
    const int co = co0 + nt*16 + m;
    const float bv = bias[co];
    float s1 = 0.f, s2 = 0.f;
    #pragma unroll
    for(int r=0;r<4;r++){
      const float v = acc[nt][r] + bv;
      y[((size_t)b*T_ + t_base + r)*Cout + co] = v;
      s1 += v; s2 += v*v;
    }
    s1 += __shfl_xor(s1, 16); s1 += __shfl_xor(s1, 32);
    s2 += __shfl_xor(s2, 16); s2 += __shfl_xor(s2, 32);
    if(q==0){ part[(wv*64 + nt*16 + m)*2+0] = s1; part[(wv*64 + nt*16 + m)*2+1] = s2; }
  }
  __syncthreads();
  if(tid < 64){
    float a1=0.f, a2=0.f;
    #pragma unroll
    for(int w2i=0; w2i<4; w2i++){ a1 += part[(w2i*64+tid)*2+0]; a2 += part[(w2i*64+tid)*2+1]; }
    atomicAdd(&bnacc[co0 + tid], a1);
    atomicAdd(&bnacc[Cout + co0 + tid], a2);
  }
}

// ---- BN + gelu (writes activated y) + per-(b,c) t-sum accum
__device__ __forceinline__ void bn_act_body(int b, int chunk, char* smemraw,
    float* __restrict__ y, const float* __restrict__ bnacc,
    const float* __restrict__ gw, const float* __restrict__ bw,
    float* __restrict__ mean_acc, int C, int write_y)
{
  const int t0 = chunk*128, tid = threadIdx.x;
  const int c = tid & (C-1), part = tid / C, np = 256 / C;
  const float cnt = (float)(B_*T_);
  const float mm = bnacc[c]/cnt;
  const float var = bnacc[C+c]/cnt - mm*mm;
  const float sc = gw[c]/sqrtf(var+1e-3f);
  const float sh = bw[c] - mm*sc;
  float s = 0.f;
  for(int t=t0+part; t<t0+128; t+=np){
    const size_t off = ((size_t)b*T_ + t)*C + c;
    float v = y[off];
    v = gelu_(v*sc + sh);
    if(write_y) y[off] = v;
    s += v;
  }
  float* rs = (float*)smemraw;
  if(np > 1){
    rs[tid]=s;
    __syncthreads();
    if(part==0) s += rs[tid+C];
  }
  if(part==0) atomicAdd(&mean_acc[b*C+c], s);
}

// ---- LSTM scan SEGMENT body: 2 waves per batch (measured-450us structure),
// steps [ts, ts+nsteps). c checkpointed to cstate[]; h restored from
// hidden[ts-1]. Dispatch boundaries provide grid-wide phase ordering.
__device__ __forceinline__ void lstm_seg_body(int b, int ts, int nsteps, char* smemraw,
    const float* __restrict__ axT, const float* __restrict__ w1,
    const float* __restrict__ w2, const float* __restrict__ b2,
    float* __restrict__ hidden, float* __restrict__ cstate)
{
  float (*hs)[148] = (float(*)[148])smemraw;
  const int tid = threadIdx.x;   // 0..127 (workers only)
  const int l = tid & 63, wv = tid >> 6;
  const int j = l >> 2, g = l & 3;
  const int hi = wv*64 + l;

  v2f w1hv[16];
  #pragma unroll
  for(int q=0;q<16;q++){
    w1hv[q].x = w1[(64 + g*32 + 2*q)*KH_ + j];
    w1hv[q].y = w1[(64 + g*32 + 2*q + 1)*KH_ + j];
  }
  v2f w2if[16], w2go[16];
  #pragma unroll
  for(int k=0;k<16;k++){
    w2if[k].x = w2[k*512 + hi];       w2if[k].y = w2[k*512 + 128 + hi];
    w2go[k].x = w2[k*512 + 256 + hi]; w2go[k].y = w2[k*512 + 384 + hi];
  }
  v2f bif, bgo;
  bif.x = b2[hi]; bif.y = b2[128+hi]; bgo.x = b2[256+hi]; bgo.y = b2[384+hi];

  const float* axr = axT + ((size_t)b*16 + j)*1024;
  float* hb = hidden + (size_t)b*T_*H_;
  const int hwi = (hi>>5)*36 + (hi&31);
  float c;
  if(ts == 0){
    for(int i=tid;i<2*148;i+=128) ((float*)hs)[i]=0.f;
    c = 0.f;
  } else {
    c = cstate[b*H_ + hi];
    hs[0][hwi] = hb[(size_t)(ts-1)*H_ + hi];
  }
  float4 axA = *(const float4*)&axr[ts];
  float4 axB = *(const float4*)&axr[ts+4];
  __syncthreads();   // barrier #1

#define LSTM_STEP(tt, axv, RB) { \
    const float* hsr = hs[RB]; \
    float* hsw = hs[1-(RB)]; \
    v2f ap0=(v2f)(0.f), ap1=(v2f)(0.f), ap2=(v2f)(0.f), ap3=(v2f)(0.f); \
    { const float4 hv = *(const float4*)&hsr[g*36 + 0];  ap0 += ((v2f){hv.x,hv.y})*w1hv[0]  + ((v2f){hv.z,hv.w})*w1hv[1]; } \
    { const float4 hv = *(const float4*)&hsr[g*36 + 4];  ap1 += ((v2f){hv.x,hv.y})*w1hv[2]  + ((v2f){hv.z,hv.w})*w1hv[3]; } \
    { const float4 hv = *(const float4*)&hsr[g*36 + 8];  ap2 += ((v2f){hv.x,hv.y})*w1hv[4]  + ((v2f){hv.z,hv.w})*w1hv[5]; } \
    { const float4 hv = *(const float4*)&hsr[g*36 + 12]; ap3 += ((v2f){hv.x,hv.y})*w1hv[6]  + ((v2f){hv.z,hv.w})*w1hv[7]; } \
    { const float4 hv = *(const float4*)&hsr[g*36 + 16]; ap0 += ((v2f){hv.x,hv.y})*w1hv[8]  + ((v2f){hv.z,hv.w})*w1hv[9]; } \
    { const float4 hv = *(const float4*)&hsr[g*36 + 20]; ap1 += ((v2f){hv.x,hv.y})*w1hv[10] + ((v2f){hv.z,hv.w})*w1hv[11]; } \
    { const float4 hv = *(const float4*)&hsr[g*36 + 24]; ap2 += ((v2f){hv.x,hv.y})*w1hv[12] + ((v2f){hv.z,hv.w})*w1hv[13]; } \
    { const float4 hv = *(const float4*)&hsr[g*36 + 28]; ap3 += ((v2f){hv.x,hv.y})*w1hv[14] + ((v2f){hv.z,hv.w})*w1hv[15]; } \
    const v2f apt = (ap0+ap1)+(ap2+ap3); \
    float a = apt.x + apt.y; \
    a += QPERM_XOR1(a); \
    a += QPERM_XOR2(a); \
    a += (axv); \
    const float g1 = a * sig_(a); \
    v2f aIF = bif, aGO = bgo; \
    _Pragma("unroll") \
    for(int k=0;k<16;k++){ \
      const float gk = __int_as_float(__builtin_amdgcn_readlane(__float_as_int(g1), 4*k)); \
      v2f gk2; gk2.x=gk; gk2.y=gk; \
      aIF += gk2 * w2if[k]; \
      aGO += gk2 * w2go[k]; \
    } \
    const float si = sig_(aIF.x); \
    const float sf = sig_(aIF.y); \
    const float tg = tanh_(aGO.x); \
    const float so = sig_(aGO.y); \
    c = sf*c + si*tg; \
    const float h = so * tanh_(c); \
    hsw[hwi] = h; \
    hb[(size_t)(tt)*H_ + hi] = h; \
    LDS_BARRIER(); \
  }

  const int te = ts + nsteps;
  for(int t0=ts;t0<te;t0+=4){
    const int tl = (t0+8 < 1020) ? (t0+8) : 1020;
    const float4 axC = *(const float4*)&axr[tl];
    LSTM_STEP(t0+0, axA.x, 0)
    LSTM_STEP(t0+1, axA.y, 1)
    LSTM_STEP(t0+2, axA.z, 0)
    LSTM_STEP(t0+3, axA.w, 1)
    axA = axB; axB = axC;
  }
#undef LSTM_STEP
  if(te < T_) cstate[b*H_ + hi] = c;
}

// ================================================================ kernels

__global__ __launch_bounds__(256) void mega0_kernel(
    const float* c1w, const float* c2w, const float* c3w,
    unsigned short* wp1, unsigned short* wp2, unsigned short* wp3,
    const float* x, const float* kw1, const float* kb1, float* axT)
{
  __shared__ __align__(16) char sm[16*68*4 + 64*16*4];
  const int bid = blockIdx.x;
  if(bid < 1280) prepack_body(bid, c1w, c2w, c3w, wp1, wp2, wp3);
  else ax_body(bid-1280, sm, x, kw1, kb1, axT);
}

// Segment kernel: blocks [0,32) lstm | [32,32+nphase) conv/bn phase |
// [+nnorm) progressive norm (rows < ts, written by previous segments) |
// [+nstile) S-Gram tiles (rings whose rows were norm'd by previous
// dispatches). Grid-wide phase ordering comes from dispatch boundaries.
// Ring decode: pair index p -> ring m=isqrt(p); idx<m -> (idx,m);
// idx<2m -> (m,idx-m); else (m,m). Ring m needs rows < (m+1)*64.
__global__ __launch_bounds__(256) void seg_kernel(
    int ts, int nsteps, int phase, int nphase, int normbase, int nnorm,
    int pairbase, int nstile,
    const float* axT, const float* kw1, const float* kw2, const float* kb2,
    float* hidden, float* cstate,
    const float* x, const unsigned short* wp1, const float* c1b, float* y1, float* bn1,
    const float* g1w, const float* b1w, float* se1_in,
    const unsigned short* wp2, const float* c2b, const float* s1w1, const float* s1w2,
    float* y2, float* bn2,
    const float* g2w, const float* b2w, float* se2_in,
    const unsigned short* wp3, const float* c3b, const float* s2w1, const float* s2w2,
    float* y3, float* bn3,
    const float* g3w, const float* b3w, float* x2,
    unsigned short* hnhi, unsigned short* hnlo, double* rowsum, double* psum)
{
  __shared__ __align__(16) char sm[sizeof(ConvS)];
  const int bid = blockIdx.x;
  if(bid < 32){
    if(nsteps == 0) return;
    if(threadIdx.x >= 128){
      const int nb = nsteps + 1;
      #pragma nounroll
      for(int i=0;i<nb;i++){ asm volatile("s_barrier" ::: "memory"); }
      return;
    }
    __builtin_amdgcn_s_setprio(1);
    lstm_seg_body(bid, ts, nsteps, sm, axT, kw1, kw2, kb2, hidden, cstate);
    return;
  }
  int cb = bid - 32;
  if(cb < nphase){
    switch(phase){
      case 0:
        conv_body(cb&15, (cb>>4)&1, cb>>5, sm, x, wp1, c1b,
                  nullptr, nullptr, nullptr, 0, y1, bn1, F_, C1_, 8);
        break;
      case 1:
        bn_act_body(cb>>3, cb&7, sm, y1, bn1, g1w, b1w, se1_in, C1_, 1);
        break;
      case 2:
        conv_body(cb&15, (cb>>4)&3, cb>>6, sm, y1, wp2, c2b,
                  se1_in, s1w1, s1w2, C1_/16, y2, bn2, C1_, C2_, 5);
        break;
      case 3:
        bn_act_body(cb>>3, cb&7, sm, y2, bn2, g2w, b2w, se2_in, C2_, 1);
        break;
      case 4:
        conv_body(cb&15, (cb>>4)&1, cb>>5, sm, y2, wp3, c3b,
                  se2_in, s2w1, s2w2, C2_/16, y3, bn3, C2_, C3_, 3);
        break;
      default:
        bn_act_body(cb>>3, cb&7, sm, y3, bn3, g3w, b3w, x2, C3_, 0);
        break;
    }
    return;
  }
  cb -= nphase;
  if(cb < nnorm){
    const int b = cb & 31, tb = cb >> 5;
    norm8_body((size_t)b*T_ + normbase + tb*8, hidden, hnhi, hnlo);
    return;
  }
  cb -= nnorm;
  if(cb < nstile){
    const int b = cb & 31;
    const int p = pairbase + (cb >> 5);
    int mr = (int)sqrtf((float)p);
    while(mr*mr > p) mr--;
    while((mr+1)*(mr+1) <= p) mr++;
    const int idx = p - mr*mr;
    int ii, jj;
    if(idx < mr){ ii = idx; jj = mr; }
    else if(idx < 2*mr){ ii = mr; jj = idx - mr; }
    else { ii = mr; jj = mr; }
    stile_body(b, ii*64, jj*64, hnhi, hnlo, rowsum, psum);
  }
}

// tail -- cluster(b) -> head1(b) -> head2(b), one block per batch.
__global__ __launch_bounds__(256) void tail_kernel(
    const double* rowsum, const double* psum, const float* hidden, float* corr, int* cuts,
    const float* eps_z, const float* eps_cat,
    const float* mu_w, const float* mu_b, const float* std_w, const float* std_b,
    const float* muc_w, const float* muc_b, const float* stdc_w, const float* stdc_b,
    float* out_mu, float* out_std, float* out_muc, float* out_stdc, float* x1,
    const float* x2, const float* fcw, const float* fcb, float* outls)
{
  __shared__ __align__(16) char sm[sizeof(CS)];
  const int b = blockIdx.x, tid = threadIdx.x;
  cluster_body(b, sm, rowsum, psum, hidden, corr, cuts);
  __syncthreads();
  head1_body(b, sm, corr, hidden, eps_z, eps_cat, mu_w, mu_b, std_w, std_b,
             muc_w, muc_b, stdc_w, stdc_b, out_mu, out_std, out_muc, out_stdc, x1);
  __syncthreads();
  struct H2 { float xa[256]; float lg[NC_]; };
  H2* s2 = (H2*)sm;
  s2->xa[tid] = (tid<128) ? x1[b*128+tid] : x2[b*128+(tid-128)]*(1.f/(float)T_);
  __syncthreads();
  if(tid<NC_){
    float s = fcb[tid];
    for(int k=0;k<256;k++) s += s2->xa[k]*fcw[k*NC_+tid];
    s2->lg[tid]=s;
  }
  __syncthreads();
  if(tid==0){
    float mx=s2->lg[0];
    for(int q=1;q<NC_;q++) mx=fmaxf(mx,s2->lg[q]);
    float se=0;
    for(int q=0;q<NC_;q++) se += __expf(s2->lg[q]-mx);
    const float lse = logf(se)+mx;
    for(int q=0;q<NC_;q++) outls[b*NC_+q] = s2->lg[q]-lse;
  }
}

// ================================================================ launch
extern "C" void kernel_launch(void* const* d_in, const int* in_sizes, int n_in,
                              void* d_out, int out_size, void* d_ws, size_t ws_size,
                              hipStream_t stream) {
  (void)in_sizes; (void)n_in; (void)out_size; (void)ws_size;
  const float* x        = (const float*)d_in[0];
  const float* eps_z    = (const float*)d_in[1];
  const float* eps_cat  = (const float*)d_in[2];
  const float* kan_w1   = (const float*)d_in[3];
  const float* kan_b1   = (const float*)d_in[4];
  const float* kan_w2   = (const float*)d_in[5];
  const float* kan_b2   = (const float*)d_in[6];
  const float* conv1_w  = (const float*)d_in[7];
  const float* conv1_b  = (const float*)d_in[8];
  const float* conv2_w  = (const float*)d_in[9];
  const float* conv2_b  = (const float*)d_in[10];
  const float* conv3_w  = (const float*)d_in[11];
  const float* conv3_b  = (const float*)d_in[12];
  const float* bn1_g    = (const float*)d_in[13];
  const float* bn1_b    = (const float*)d_in[14];
  const float* bn2_g    = (const float*)d_in[15];
  const float* bn2_b    = (const float*)d_in[16];
  const float* bn3_g    = (const float*)d_in[17];
  const float* bn3_b    = (const float*)d_in[18];
  const float* se1_w1   = (const float*)d_in[19];
  const float* se1_w2   = (const float*)d_in[20];
  const float* se2_w1   = (const float*)d_in[21];
  const float* se2_w2   = (const float*)d_in[22];
  const float* fc_mu_w  = (const float*)d_in[23];
  const float* fc_mu_b  = (const float*)d_in[24];
  const float* fc_std_w = (const float*)d_in[25];
  const float* fc_std_b = (const float*)d_in[26];
  const float* fc_muc_w = (const float*)d_in[27];
  const float* fc_muc_b = (const float*)d_in[28];
  const float* fc_stdc_w= (const float*)d_in[29];
  const float* fc_stdc_b= (const float*)d_in[30];
  const float* fc_w     = (const float*)d_in[31];
  const float* fc_b     = (const float*)d_in[32];

  float* out = (float*)d_out;
  float* out_ls   = out;
  float* out_mu   = out + 320;
  float* out_std  = out + 320 + 4096;
  float* out_muc  = out + 320 + 2*4096;
  float* out_stdc = out + 320 + 3*4096;

  float* ws = (float*)d_ws;
  const size_t SZ_HID = (size_t)B_*T_*H_;
  const size_t SZ_Y1  = (size_t)B_*T_*C1_;
  const size_t SZ_Y2  = (size_t)B_*T_*C2_;
  float*  hidden = ws;                      // [b][t][H] — never aliased
  float*  y1     = hidden + SZ_HID;         // conv1 out; reused as y3 after conv2
  float*  y2     = y1 + SZ_Y1;
  double* rowsum = (double*)(y2 + SZ_Y2);
  double* psum   = rowsum + (size_t)B_*T_;
  float*  corr   = (float*)(psum + (size_t)B_*T_);
  float*  x1     = corr + (size_t)B_*H_;
  float*  bnbuf  = x1 + (size_t)B_*H_;      // zeroed region starts here
  float*  bn1    = bnbuf;
  float*  bn2    = bnbuf + 2*C1_;
  float*  bn3    = bnbuf + 2*C1_ + 2*C2_;
  float*  se1_in = bnbuf + 1024;
  float*  se2_in = se1_in + (size_t)B_*C1_;
  float*  x2     = se2_in + (size_t)B_*C2_;
  int*    cuts   = (int*)(x2 + (size_t)B_*C3_);
  float*  cstate = (float*)(cuts + B_);     // lstm c checkpoint [B][H]
  float*  axbuf  = cstate + (size_t)B_*H_;  // axT: B*16*T
  unsigned short* wp1 = (unsigned short*)(axbuf + (size_t)B_*16*T_);
  unsigned short* wp2 = wp1 + (size_t)C1_*F_*8;
  unsigned short* wp3 = wp2 + (size_t)C2_*C1_*5;
  unsigned short* hnhi = wp3 + (size_t)C3_*C2_*3;
  unsigned short* hnlo = hnhi + (size_t)B_*T_*H_;
  float*  y3     = y1;   // y1 dead after conv2 phase; conv3 reuses it

  // zero bn accumulators + se/x2 t-sum accumulators; zero rowsum/psum
  // (S-Gram now accumulates via atomics)
  hipMemsetAsync(bnbuf, 0, (size_t)(1024 + B_*C1_ + B_*C2_ + B_*C3_)*sizeof(float), stream);
  hipMemsetAsync(rowsum, 0, (size_t)2*B_*T_*sizeof(double), stream);

  // D0: prepack (1280) + ax (2048)
  mega0_kernel<<<3328, 256, 0, stream>>>(conv1_w, conv2_w, conv3_w, wp1, wp2, wp3,
                                         x, kan_w1, kan_b1, axbuf);

  // D1..D6: lstm segments + conv phases + progressive norm + S tiles.
  // Ring m usable at dispatch k iff (m+1)*64 <= rows norm'd before k.
  #define SEG_ARGS axbuf, kan_w1, kan_w2, kan_b2, hidden, cstate, \
      x, wp1, conv1_b, y1, bn1, bn1_g, bn1_b, se1_in, \
      wp2, conv2_b, se1_w1, se1_w2, y2, bn2, bn2_g, bn2_b, se2_in, \
      wp3, conv3_b, se2_w1, se2_w2, y3, bn3, bn3_g, bn3_b, x2, \
      hnhi, hnlo, rowsum, psum
  //                                        ts  nst ph  nph  nb    nn    pb   nst
  seg_kernel<<<32+1024,           256,0,stream>>>(  0,144, 0,1024,   0,    0,   0,    0, SEG_ARGS);
  seg_kernel<<<32+256,            256,0,stream>>>(144, 64, 1, 256,   0,    0,   0,    0, SEG_ARGS);
  seg_kernel<<<32+2048+832,       256,0,stream>>>(208,384, 2,2048,   0,  832,   0,    0, SEG_ARGS);
  seg_kernel<<<32+256+1536+288,   256,0,stream>>>(592, 64, 3, 256, 208, 1536,   0,  288, SEG_ARGS);
  seg_kernel<<<32+1024+256+2304,  256,0,stream>>>(656,240, 4,1024, 592,  256,   9, 2304, SEG_ARGS);
  seg_kernel<<<32+256+960+608,    256,0,stream>>>(896,128, 5, 256, 656,  960,  81,  608, SEG_ARGS);
  // D7: final norm chunk (t in [896,1024)) + rings 10..13 (rows < 896 ok)
  seg_kernel<<<32+512+3072,       256,0,stream>>>(  0,  0,-1,   0, 896,  512, 100, 3072, SEG_ARGS);
  // D8: rings 14..15 (need rows >= 896, norm'd in D7)
  seg_kernel<<<32+1920,           256,0,stream>>>(  0,  0,-1,   0,   0,    0, 196, 1920, SEG_ARGS);
  #undef SEG_ARGS

  // D9: tail (cluster+head1+head2, 32)
  tail_kernel<<<B_, 256, 0, stream>>>(rowsum, psum, hidden, corr, cuts,
      eps_z, eps_cat,
      fc_mu_w, fc_mu_b, fc_std_w, fc_std_b, fc_muc_w, fc_muc_b, fc_stdc_w, fc_stdc_b,
      out_mu, out_std, out_muc, out_stdc, x1,
      x2, fc_w, fc_b, out_ls);
}

// Round 9
// 773.396 us; speedup vs baseline: 1.0985x; 1.0985x over previous
//
#include <hip/hip_runtime.h>
#include <math.h>

#define B_ 32
#define T_ 1024
#define F_ 64
#define H_ 128
#define D_ 192
#define KH_ 16
#define C1_ 128
#define C2_ 256
#define C3_ 128
#define NC_ 10

typedef float v2f __attribute__((ext_vector_type(2)));
typedef float f32x4 __attribute__((ext_vector_type(4)));
typedef __bf16 bfrag __attribute__((ext_vector_type(8)));

__device__ __forceinline__ float sig_(float x){ return 1.f/(1.f+__expf(-x)); }
__device__ __forceinline__ float tanh_(float x){ return 1.f - 2.f/(__expf(2.f*x)+1.f); }
__device__ __forceinline__ float gelu_(float x){ return 0.5f*x*(1.f+erff(x*0.70710678118654752f)); }
__device__ __forceinline__ float softplus_(float x){ return fmaxf(x,0.f) + log1pf(__expf(-fabsf(x))); }

__device__ __forceinline__ unsigned bfpack(float a, float b){
  unsigned ua = __float_as_uint(a), ub = __float_as_uint(b);
  ua = ua + 0x7FFFu + ((ua>>16)&1u);
  ub = ub + 0x7FFFu + ((ub>>16)&1u);
  return (ua>>16) | (ub & 0xFFFF0000u);
}
__device__ __forceinline__ unsigned short bf1(float a){
  unsigned ua = __float_as_uint(a);
  ua = ua + 0x7FFFu + ((ua>>16)&1u);
  return (unsigned short)(ua>>16);
}
__device__ __forceinline__ float bf2f(unsigned short h){
  return __uint_as_float(((unsigned)h)<<16);
}

#define QPERM_XOR1(x) __int_as_float(__builtin_amdgcn_mov_dpp(__float_as_int(x), 0xB1, 0xF, 0xF, true))
#define QPERM_XOR2(x) __int_as_float(__builtin_amdgcn_mov_dpp(__float_as_int(x), 0x4E, 0xF, 0xF, true))

#define LDS_BARRIER() asm volatile("s_waitcnt lgkmcnt(0)\n\ts_barrier" ::: "memory")

// ================================================================ bodies

// ---- ax precompute (transposed out: axT[b][j][t])
__device__ __forceinline__ void ax_body(int blk, char* smemraw,
    const float* __restrict__ x, const float* __restrict__ w1, const float* __restrict__ b1,
    float* __restrict__ axT)
{
  struct AxS { float xs[16][68]; float w1s[64][16]; };
  AxS* sm = (AxS*)smemraw;
  const int bt0 = blk*16;
  const int tid = threadIdx.x;
  for(int i=tid;i<64*16;i+=256){ sm->w1s[i>>4][i&15] = w1[i]; }
  for(int i=tid;i<16*64;i+=256){ const int r=i>>6, d=i&63; sm->xs[r][d] = x[(size_t)(bt0+r)*64 + d]; }
  __syncthreads();
  const int r = tid>>4, j = tid&15;
  float s = b1[j];
  #pragma unroll
  for(int d=0; d<64; d++) s += sm->xs[r][d]*sm->w1s[d][j];
  const int bt = bt0 + r;
  axT[((size_t)(bt>>10)*16 + j)*1024 + (bt&1023)] = s;
}

// ---- weight prepack (bf16 MFMA B-fragment blocks, all 3 convs)
__device__ __forceinline__ void prepack_body(int blk,
    const float* __restrict__ w1s, const float* __restrict__ w2s, const float* __restrict__ w3s,
    unsigned short* __restrict__ wp1, unsigned short* __restrict__ wp2, unsigned short* __restrict__ wp3)
{
  int e = blk*256 + threadIdx.x;
  if(e >= 65536+163840+98304) return;
  const float* w; unsigned short* wp; int Cout, Cin, Kw;
  if(e < 65536){ w=w1s; wp=wp1; Cout=C1_; Cin=F_;  Kw=8; }
  else if(e < 65536+163840){ e-=65536; w=w2s; wp=wp2; Cout=C2_; Cin=C1_; Kw=5; }
  else { e-=229376; w=w3s; wp=wp3; Cout=C3_; Cin=C2_; Kw=3; }
  const int co = e/(Cin*Kw);
  const int rem = e - co*(Cin*Kw);
  const int ci = rem/Kw, kw = rem - ci*Kw;
  const int off = (((ci>>5)*Kw + kw)*(Cout>>4) + (co>>4))*512 + ((co&15)*4 + ((ci>>3)&3))*8 + (ci&7);
  wp[off] = bf1(w[e]);
}

// ---- row norms + write normalized rows as bf16 hi/lo
__device__ __forceinline__ void norm_body(int blk,
    const float* __restrict__ hidden,
    unsigned short* __restrict__ hnhi, unsigned short* __restrict__ hnlo)
{
  const int row = blk*8 + (threadIdx.x>>5);
  const int l = threadIdx.x&31;
  const float* hr = hidden + (size_t)row*H_;
  float s = 0.f;
  for(int k=l;k<H_;k+=32){ float v=hr[k]; s+=v*v; }
  #pragma unroll
  for(int m=16;m>=1;m>>=1) s += __shfl_xor(s, m, 64);
  const float inv = 1.f/fmaxf(sqrtf(s), 1e-8f);
  const float4 v = *(const float4*)&hr[l*4];
  const float f0=v.x*inv, f1=v.y*inv, f2=v.z*inv, f3=v.w*inv;
  const unsigned short h0=bf1(f0), h1=bf1(f1), h2=bf1(f2), h3=bf1(f3);
  uint2 phi; phi.x = (unsigned)h0 | ((unsigned)h1<<16); phi.y = (unsigned)h2 | ((unsigned)h3<<16);
  *(uint2*)&hnhi[(size_t)row*H_ + l*4] = phi;
  const unsigned short g0=bf1(f0-bf2f(h0)), g1=bf1(f1-bf2f(h1)), g2=bf1(f2-bf2f(h2)), g3=bf1(f3-bf2f(h3));
  uint2 plo; plo.x = (unsigned)g0 | ((unsigned)g1<<16); plo.y = (unsigned)g2 | ((unsigned)g3<<16);
  *(uint2*)&hnlo[(size_t)row*H_ + l*4] = plo;
}

// ---- S rowsums via bf16 MFMA, SYMMETRY-HALVED (R8 post-mortem).
// S[i][j]=S[j][i] exactly (hi/lo split Gram is commutative: Ah.Bh+Al.Bh+Ah.Bl).
// Compute only i0<=j0 tile pairs (136 of 256 per batch, -47% MFMA+staging).
// Off-diagonal tile: row-sums -> rowsum[i-rows]; column-sums -> rowsum[j-rows]
// AND psum[j-rows] (blocks disjoint, all gi<gj). Diagonal: old path.
// Load balance: bundle k = tiles{i0=k} (16-k) + tiles{i0=15-k} (k+1) = 17,
// split 9/8 over two blocks -> 512 blocks x <=9 iters (was 512 x 16), same
// 78KB-LDS 2-blocks/CU single residency wave -> ~0.6x duration.
// Accumulation: zeroed buffers + native f64 atomics (order-robustness
// demonstrated by R8's passing run).
struct SS {
  unsigned short Ahi[64*136];
  unsigned short Alo[64*136];
  unsigned short Bhi[64*136];
  unsigned short Blo[64*136];
  double red[64][17];
};
__device__ __forceinline__ void s_sym_body(int blk, char* smemraw,
    const unsigned short* __restrict__ hnhi, const unsigned short* __restrict__ hnlo,
    double* __restrict__ rowsum, double* __restrict__ psum)
{
  SS* sm = (SS*)smemraw;
  const int b = blk >> 4;
  const int k2 = blk & 15, k = k2 >> 1, half = k2 & 1;
  const int n1 = 16 - k;                  // tiles with i0=k in this bundle
  const int start = half ? 9 : 0;
  const int end   = half ? 17 : 9;
  const int tid = threadIdx.x, l = tid & 63, wv = tid >> 6;
  const int m = l & 15, q = l >> 4;
  const int arow = (wv*16 + m)*136;
  double* red = &sm->red[0][0];           // reused as [4][64] col partials

  int cur_i0 = -1;
  for(int idx=start; idx<end; idx++){
    int i0, j0;
    if(idx < n1){ i0 = k*64;      j0 = (k+idx)*64; }
    else        { i0 = (15-k)*64; j0 = (15-k + (idx-n1))*64; }
    __syncthreads();
    if(i0 != cur_i0){
      cur_i0 = i0;
      const uint4* ghi = (const uint4*)(hnhi + ((size_t)b*T_ + i0)*H_);
      const uint4* glo = (const uint4*)(hnlo + ((size_t)b*T_ + i0)*H_);
      for(int t2=tid; t2<64*16; t2+=256){
        const int r = t2>>4, c8 = t2&15;
        *(uint4*)&sm->Ahi[r*136 + c8*8] = ghi[r*16 + c8];
        *(uint4*)&sm->Alo[r*136 + c8*8] = glo[r*16 + c8];
      }
    }
    {
      const uint4* ghi = (const uint4*)(hnhi + ((size_t)b*T_ + j0)*H_);
      const uint4* glo = (const uint4*)(hnlo + ((size_t)b*T_ + j0)*H_);
      for(int t2=tid; t2<64*16; t2+=256){
        const int r = t2>>4, c8 = t2&15;
        *(uint4*)&sm->Bhi[r*136 + c8*8] = ghi[r*16 + c8];
        *(uint4*)&sm->Blo[r*136 + c8*8] = glo[r*16 + c8];
      }
    }
    __syncthreads();

    f32x4 acc[4];
    #pragma unroll
    for(int nt=0;nt<4;nt++) acc[nt] = (f32x4)(0.f);
    #pragma unroll
    for(int kc=0;kc<4;kc++){
      const bfrag Ah = *(const bfrag*)&sm->Ahi[arow + kc*32 + q*8];
      const bfrag Al = *(const bfrag*)&sm->Alo[arow + kc*32 + q*8];
      #pragma unroll
      for(int nt=0;nt<4;nt++){
        const int brow = (nt*16 + m)*136 + kc*32 + q*8;
        const bfrag Bh = *(const bfrag*)&sm->Bhi[brow];
        const bfrag Bl = *(const bfrag*)&sm->Blo[brow];
        acc[nt] = __builtin_amdgcn_mfma_f32_16x16x32_bf16(Ah, Bh, acc[nt], 0, 0, 0);
        acc[nt] = __builtin_amdgcn_mfma_f32_16x16x32_bf16(Al, Bh, acc[nt], 0, 0, 0);
        acc[nt] = __builtin_amdgcn_mfma_f32_16x16x32_bf16(Ah, Bl, acc[nt], 0, 0, 0);
      }
    }

    if(i0 == j0){
      // diagonal tile: rows get row-sums (skip gi==gj); psum over gj<gi
      double rs[4]={0,0,0,0}, ps[4]={0,0,0,0};
      #pragma unroll
      for(int nt=0;nt<4;nt++){
        const int gj = j0 + nt*16 + m;
        #pragma unroll
        for(int r=0;r<4;r++){
          const int gi = i0 + wv*16 + q*4 + r;
          if(gi == gj) continue;
          const float sv = __expf(-5.5f*(1.f - acc[nt][r]));
          rs[r] += (double)sv;
          if(gj < gi) ps[r] += (double)sv;
        }
      }
      #pragma unroll
      for(int r=0;r<4;r++){
        #pragma unroll
        for(int mk=1;mk<16;mk<<=1){
          rs[r] += __shfl_xor(rs[r], mk, 64);
          ps[r] += __shfl_xor(ps[r], mk, 64);
        }
      }
      if(m == 0){
        const size_t gbase = (size_t)b*T_ + i0 + wv*16 + q*4;
        #pragma unroll
        for(int r=0;r<4;r++){
          unsafeAtomicAdd(&rowsum[gbase + r], rs[r]);
          unsafeAtomicAdd(&psum[gbase + r], ps[r]);
        }
      }
    } else {
      // off-diagonal (i0<j0): rows <- row-sums; cols -> rowsum+psum[j-rows]
      double rs[4]={0,0,0,0}, cs[4]={0,0,0,0};
      #pragma unroll
      for(int nt=0;nt<4;nt++){
        double csn = 0.0;
        #pragma unroll
        for(int r=0;r<4;r++){
          const float sv = __expf(-5.5f*(1.f - acc[nt][r]));
          rs[r] += (double)sv;
          csn   += (double)sv;
        }
        cs[nt] = csn;
      }
      #pragma unroll
      for(int r=0;r<4;r++){
        #pragma unroll
        for(int mk=1;mk<16;mk<<=1) rs[r] += __shfl_xor(rs[r], mk, 64);
      }
      if(m == 0){
        const size_t gbase = (size_t)b*T_ + i0 + wv*16 + q*4;
        #pragma unroll
        for(int r=0;r<4;r++) unsafeAtomicAdd(&rowsum[gbase + r], rs[r]);
      }
      #pragma unroll
      for(int nt=0;nt<4;nt++){
        cs[nt] += __shfl_xor(cs[nt], 16, 64);
        cs[nt] += __shfl_xor(cs[nt], 32, 64);
      }
      if(q == 0){
        #pragma unroll
        for(int nt=0;nt<4;nt++) red[wv*64 + nt*16 + m] = cs[nt];
      }
      __syncthreads();
      if(tid < 64){
        const double v = red[tid] + red[64+tid] + red[128+tid] + red[192+tid];
        unsafeAtomicAdd(&rowsum[(size_t)b*T_ + j0 + tid], v);
        unsafeAtomicAdd(&psum[(size_t)b*T_ + j0 + tid], v);
      }
    }
  }
}

// ---- cluster: prefix+dist+argmax+corr
struct CS {
  double sr[256]; double sp[256]; double bd[256]; double totR;
  float c2[2][128]; int bidx[256]; int cut;
};
__device__ __forceinline__ void cluster_body(int b, char* smemraw,
    const double* __restrict__ rowsum, const double* __restrict__ psum,
    const float* __restrict__ hidden, float* __restrict__ corr, int* __restrict__ cuts)
{
  CS* sm = (CS*)smemraw;
  const int tid = threadIdx.x;
  const double* r = rowsum + (size_t)b*T_;
  const double* p = psum + (size_t)b*T_;
  double r4[4], p4[4];
  #pragma unroll
  for(int q=0;q<4;q++){ r4[q]=r[tid*4+q]; p4[q]=p[tid*4+q]; }
  sm->sr[tid]=r4[0]+r4[1]+r4[2]+r4[3];
  sm->sp[tid]=p4[0]+p4[1]+p4[2]+p4[3];
  __syncthreads();
  if(tid==0){
    double ar=0, ap=0;
    for(int i=0;i<256;i++){ double tr=sm->sr[i], tp=sm->sp[i]; sm->sr[i]=ar; sm->sp[i]=ap; ar+=tr; ap+=tp; }
    sm->totR = ar;
  }
  __syncthreads();
  double cr = sm->sr[tid], cp = sm->sp[tid];
  const double full = sm->totR;
  double best = -1e308; int bi = 1;
  #pragma unroll
  for(int q=0;q<4;q++){
    cr += r4[q]; cp += p4[q];
    const int i = 4*tid + q + 1;
    if(i < T_){
      const double TL = 2.0*cp;
      const double TRv = cr - TL;
      const double BR = full - TL - 2.0*TRv;
      const double di = (double)i, dn = (double)(T_-i);
      const double dist = TL/(di*di) + BR/(dn*dn) - (2.0*TRv)/(di*dn);
      if(dist > best){ best=dist; bi=i; }
    }
  }
  sm->bd[tid]=best; sm->bidx[tid]=bi;
  __syncthreads();
  if(tid==0){
    double bb=-1e308; int ii=1;
    for(int q=0;q<256;q++){ if(sm->bd[q]>bb){ bb=sm->bd[q]; ii=sm->bidx[q]; } }
    sm->cut=ii; cuts[b]=ii;
  }
  __syncthreads();
  const int cut = sm->cut;
  const int h = tid&127, half = tid>>7;
  float s=0.f;
  const float* hb = hidden + (size_t)b*T_*H_;
  #pragma unroll 4
  for(int t=half; t<cut; t+=2) s += hb[(size_t)t*H_ + h];
  sm->c2[half][h]=s;
  __syncthreads();
  if(tid<128) corr[b*H_+tid] = (sm->c2[0][tid]+sm->c2[1][tid])/(float)cut;
}

// ---- VAE head1 (first 128 threads work)
__device__ __forceinline__ void head1_body(int b, char* smemraw,
    const float* __restrict__ corr, const float* __restrict__ hidden,
    const float* __restrict__ eps_z, const float* __restrict__ eps_cat,
    const float* __restrict__ mu_w, const float* __restrict__ mu_b,
    const float* __restrict__ std_w, const float* __restrict__ std_b,
    const float* __restrict__ muc_w, const float* __restrict__ muc_b,
    const float* __restrict__ stdc_w, const float* __restrict__ stdc_b,
    float* __restrict__ out_mu, float* __restrict__ out_std,
    float* __restrict__ out_muc, float* __restrict__ out_stdc, float* __restrict__ x1)
{
  struct H1 { float cs[128]; float xz[256]; };
  H1* sm = (H1*)smemraw;
  const int h = threadIdx.x;
  if(h<128){
    sm->cs[h]=corr[b*H_+h];
    sm->xz[h]=hidden[((size_t)b*T_ + (T_-1))*H_ + h];
  }
  __syncthreads();
  if(h<128){
    float m=mu_b[h], sdv=std_b[h];
    for(int k=0;k<H_;k++){ const float cv=sm->cs[k]; m+=cv*mu_w[k*H_+h]; sdv+=cv*std_w[k*H_+h]; }
    const float stdv = softplus_(sdv);
    out_mu[b*H_+h]=m; out_std[b*H_+h]=stdv;
    sm->xz[128+h] = m + stdv*eps_z[b*H_+h];
  }
  __syncthreads();
  if(h<128){
    float mc=muc_b[h], sc=stdc_b[h];
    for(int k=0;k<256;k++){ const float v=sm->xz[k]; mc+=v*muc_w[k*H_+h]; sc+=v*stdc_w[k*H_+h]; }
    const float stdc = softplus_(sc);
    out_muc[b*H_+h]=mc; out_stdc[b*H_+h]=stdc;
    x1[b*H_+h]=mc + stdc*eps_cat[b*H_+h];
  }
}

// ---- causal conv via bf16 MFMA + fused BN partials + optional inline SE scale
struct ConvS {
  float sescale[256];
  float seh[16];
  unsigned short xs[72*40];   // bf16 staging; reused as float part[]/ms[]
};
__device__ __forceinline__ void conv_body(int bx, int by, int bz, char* smemraw,
    const float* __restrict__ in, const unsigned short* __restrict__ wp,
    const float* __restrict__ bias,
    const float* __restrict__ se_in, const float* __restrict__ se_w1,
    const float* __restrict__ se_w2, int seR,
    float* __restrict__ y, float* __restrict__ bnacc, int Cin, int Cout, int Kw)
{
  ConvS* sm = (ConvS*)smemraw;
  unsigned short* xs = sm->xs;
  const int b = bz, t0 = bx*64, co0 = by*64;
  const int tid = threadIdx.x, l = tid&63, wv = tid>>6;
  const int q = l>>4, m = l&15;
  const int TW = 64 + Kw - 1;
  const int abase = (wv*16 + m)*40 + q*8;
  const int boff = (m*4 + q)*8;
  const bool use_se = (se_in != nullptr);

  if(use_se){
    float* ms = (float*)xs;
    if(tid<Cin) ms[tid] = se_in[b*Cin+tid] * (1.f/(float)T_);
    __syncthreads();
    if(tid<seR){ float s=0.f; for(int k=0;k<Cin;k++) s += ms[k]*se_w1[k*seR+tid]; sm->seh[tid]=fmaxf(s,0.f); }
    __syncthreads();
    if(tid<Cin){ float s=0.f; for(int k=0;k<seR;k++) s += sm->seh[k]*se_w2[k*Cin+tid]; sm->sescale[tid]=sig_(s); }
  }

  f32x4 acc[4];
  #pragma unroll
  for(int nt=0;nt<4;nt++) acc[nt] = (f32x4)(0.f);

  const int nchunks = Cin >> 5;
  for(int cc=0; cc<nchunks; cc++){
    __syncthreads();
    for(int idx=tid; idx<TW*8; idx+=256){
      const int r = idx>>3, c4 = (idx&7)*4;
      const int tg = t0 - (Kw-1) + r;
      uint2 pk = make_uint2(0u, 0u);
      if(tg >= 0){
        float4 v = *(const float4*)&in[((size_t)b*T_ + tg)*Cin + cc*32 + c4];
        if(use_se){
          const float4 s4 = *(const float4*)&sm->sescale[cc*32 + c4];
          v.x*=s4.x; v.y*=s4.y; v.z*=s4.z; v.w*=s4.w;
        }
        pk.x = bfpack(v.x, v.y); pk.y = bfpack(v.z, v.w);
      }
      *(uint2*)&xs[r*40 + c4] = pk;
    }
    __syncthreads();
    for(int kw=0; kw<Kw; kw++){
      const bfrag Af = *(const bfrag*)&xs[abase + kw*40];
      #pragma unroll
      for(int nt=0; nt<4; nt++){
        const unsigned short* wpp = wp + ((size_t)((cc*Kw + kw)*(Cout>>4) + (by*4 + nt)))*512 + boff;
        const bfrag Bf = *(const bfrag*)wpp;
        acc[nt] = __builtin_amdgcn_mfma_f32_16x16x32_bf16(Af, Bf, acc[nt], 0, 0, 0);
      }
    }
  }
  __syncthreads();
  float* part = (float*)xs;
  const int t_base = t0 + wv*16 + q*4;
  #pragma unroll
  for(int nt=0; nt<4; nt++){
    const int co = co0 + nt*16 + m;
    const float bv = bias[co];
    float s1 = 0.f, s2 = 0.f;
    #pragma unroll
    for(int r=0;r<4;r++){
      const float v = acc[nt][r] + bv;
      y[((size_t)b*T_ + t_base + r)*Cout + co] = v;
      s1 += v; s2 += v*v;
    }
    s1 += __shfl_xor(s1, 16); s1 += __shfl_xor(s1, 32);
    s2 += __shfl_xor(s2, 16); s2 += __shfl_xor(s2, 32);
    if(q==0){ part[(wv*64 + nt*16 + m)*2+0] = s1; part[(wv*64 + nt*16 + m)*2+1] = s2; }
  }
  __syncthreads();
  if(tid < 64){
    float a1=0.f, a2=0.f;
    #pragma unroll
    for(int w2i=0; w2i<4; w2i++){ a1 += part[(w2i*64+tid)*2+0]; a2 += part[(w2i*64+tid)*2+1]; }
    atomicAdd(&bnacc[co0 + tid], a1);
    atomicAdd(&bnacc[Cout + co0 + tid], a2);
  }
}

// ---- BN + gelu (writes activated y) + per-(b,c) t-sum accum
__device__ __forceinline__ void bn_act_body(int b, int chunk, char* smemraw,
    float* __restrict__ y, const float* __restrict__ bnacc,
    const float* __restrict__ gw, const float* __restrict__ bw,
    float* __restrict__ mean_acc, int C, int write_y)
{
  const int t0 = chunk*128, tid = threadIdx.x;
  const int c = tid & (C-1), part = tid / C, np = 256 / C;
  const float cnt = (float)(B_*T_);
  const float mm = bnacc[c]/cnt;
  const float var = bnacc[C+c]/cnt - mm*mm;
  const float sc = gw[c]/sqrtf(var+1e-3f);
  const float sh = bw[c] - mm*sc;
  float s = 0.f;
  for(int t=t0+part; t<t0+128; t+=np){
    const size_t off = ((size_t)b*T_ + t)*C + c;
    float v = y[off];
    v = gelu_(v*sc + sh);
    if(write_y) y[off] = v;
    s += v;
  }
  float* rs = (float*)smemraw;
  if(np > 1){
    rs[tid]=s;
    __syncthreads();
    if(part==0) s += rs[tid+C];
  }
  if(part==0) atomicAdd(&mean_acc[b*C+c], s);
}

// ---- LSTM scan SEGMENT body: 2 waves per batch (measured-450us structure),
// steps [ts, ts+nsteps). c checkpointed to cstate[]; h restored from
// hidden[ts-1]. Dispatch boundaries provide grid-wide phase ordering.
__device__ __forceinline__ void lstm_seg_body(int b, int ts, int nsteps, char* smemraw,
    const float* __restrict__ axT, const float* __restrict__ w1,
    const float* __restrict__ w2, const float* __restrict__ b2,
    float* __restrict__ hidden, float* __restrict__ cstate)
{
  float (*hs)[148] = (float(*)[148])smemraw;
  const int tid = threadIdx.x;   // 0..127 (workers only)
  const int l = tid & 63, wv = tid >> 6;
  const int j = l >> 2, g = l & 3;
  const int hi = wv*64 + l;

  v2f w1hv[16];
  #pragma unroll
  for(int q=0;q<16;q++){
    w1hv[q].x = w1[(64 + g*32 + 2*q)*KH_ + j];
    w1hv[q].y = w1[(64 + g*32 + 2*q + 1)*KH_ + j];
  }
  v2f w2if[16], w2go[16];
  #pragma unroll
  for(int k=0;k<16;k++){
    w2if[k].x = w2[k*512 + hi];       w2if[k].y = w2[k*512 + 128 + hi];
    w2go[k].x = w2[k*512 + 256 + hi]; w2go[k].y = w2[k*512 + 384 + hi];
  }
  v2f bif, bgo;
  bif.x = b2[hi]; bif.y = b2[128+hi]; bgo.x = b2[256+hi]; bgo.y = b2[384+hi];

  const float* axr = axT + ((size_t)b*16 + j)*1024;
  float* hb = hidden + (size_t)b*T_*H_;
  const int hwi = (hi>>5)*36 + (hi&31);
  float c;
  if(ts == 0){
    for(int i=tid;i<2*148;i+=128) ((float*)hs)[i]=0.f;
    c = 0.f;
  } else {
    c = cstate[b*H_ + hi];
    hs[0][hwi] = hb[(size_t)(ts-1)*H_ + hi];
  }
  float4 axA = *(const float4*)&axr[ts];
  float4 axB = *(const float4*)&axr[ts+4];
  __syncthreads();   // barrier #1

#define LSTM_STEP(tt, axv, RB) { \
    const float* hsr = hs[RB]; \
    float* hsw = hs[1-(RB)]; \
    v2f ap0=(v2f)(0.f), ap1=(v2f)(0.f), ap2=(v2f)(0.f), ap3=(v2f)(0.f); \
    { const float4 hv = *(const float4*)&hsr[g*36 + 0];  ap0 += ((v2f){hv.x,hv.y})*w1hv[0]  + ((v2f){hv.z,hv.w})*w1hv[1]; } \
    { const float4 hv = *(const float4*)&hsr[g*36 + 4];  ap1 += ((v2f){hv.x,hv.y})*w1hv[2]  + ((v2f){hv.z,hv.w})*w1hv[3]; } \
    { const float4 hv = *(const float4*)&hsr[g*36 + 8];  ap2 += ((v2f){hv.x,hv.y})*w1hv[4]  + ((v2f){hv.z,hv.w})*w1hv[5]; } \
    { const float4 hv = *(const float4*)&hsr[g*36 + 12]; ap3 += ((v2f){hv.x,hv.y})*w1hv[6]  + ((v2f){hv.z,hv.w})*w1hv[7]; } \
    { const float4 hv = *(const float4*)&hsr[g*36 + 16]; ap0 += ((v2f){hv.x,hv.y})*w1hv[8]  + ((v2f){hv.z,hv.w})*w1hv[9]; } \
    { const float4 hv = *(const float4*)&hsr[g*36 + 20]; ap1 += ((v2f){hv.x,hv.y})*w1hv[10] + ((v2f){hv.z,hv.w})*w1hv[11]; } \
    { const float4 hv = *(const float4*)&hsr[g*36 + 24]; ap2 += ((v2f){hv.x,hv.y})*w1hv[12] + ((v2f){hv.z,hv.w})*w1hv[13]; } \
    { const float4 hv = *(const float4*)&hsr[g*36 + 28]; ap3 += ((v2f){hv.x,hv.y})*w1hv[14] + ((v2f){hv.z,hv.w})*w1hv[15]; } \
    const v2f apt = (ap0+ap1)+(ap2+ap3); \
    float a = apt.x + apt.y; \
    a += QPERM_XOR1(a); \
    a += QPERM_XOR2(a); \
    a += (axv); \
    const float g1 = a * sig_(a); \
    v2f aIF = bif, aGO = bgo; \
    _Pragma("unroll") \
    for(int k=0;k<16;k++){ \
      const float gk = __int_as_float(__builtin_amdgcn_readlane(__float_as_int(g1), 4*k)); \
      v2f gk2; gk2.x=gk; gk2.y=gk; \
      aIF += gk2 * w2if[k]; \
      aGO += gk2 * w2go[k]; \
    } \
    const float si = sig_(aIF.x); \
    const float sf = sig_(aIF.y); \
    const float tg = tanh_(aGO.x); \
    const float so = sig_(aGO.y); \
    c = sf*c + si*tg; \
    const float h = so * tanh_(c); \
    hsw[hwi] = h; \
    hb[(size_t)(tt)*H_ + hi] = h; \
    LDS_BARRIER(); \
  }

  const int te = ts + nsteps;
  for(int t0=ts;t0<te;t0+=4){
    const int tl = (t0+8 < 1020) ? (t0+8) : 1020;
    const float4 axC = *(const float4*)&axr[tl];
    LSTM_STEP(t0+0, axA.x, 0)
    LSTM_STEP(t0+1, axA.y, 1)
    LSTM_STEP(t0+2, axA.z, 0)
    LSTM_STEP(t0+3, axA.w, 1)
    axA = axB; axB = axC;
  }
#undef LSTM_STEP
  if(te < T_) cstate[b*H_ + hi] = c;
}

// ================================================================ kernels

__global__ __launch_bounds__(256) void mega0_kernel(
    const float* c1w, const float* c2w, const float* c3w,
    unsigned short* wp1, unsigned short* wp2, unsigned short* wp3,
    const float* x, const float* kw1, const float* kb1, float* axT)
{
  __shared__ __align__(16) char sm[16*68*4 + 64*16*4];
  const int bid = blockIdx.x;
  if(bid < 1280) prepack_body(bid, c1w, c2w, c3w, wp1, wp2, wp3);
  else ax_body(bid-1280, sm, x, kw1, kb1, axT);
}

// D1..D6: lstm segment (blocks 0-31) + one conv-branch phase.
// Dispatch boundaries provide grid-wide phase ordering (conv1 -> bn_act1
// -> conv2 -> bn_act2 -> conv3 -> bn3). Each phase fits its lstm-segment
// shadow (R5: co-scheduled conv work costs lstm only ~+7us). lstm workers
// at setprio(1); idle lstm waves spin count-matched barriers (1+nsteps).
__global__ __launch_bounds__(256) void seg_kernel(
    int ts, int nsteps, int phase,
    const float* axT, const float* kw1, const float* kw2, const float* kb2,
    float* hidden, float* cstate,
    const float* x, const unsigned short* wp1, const float* c1b, float* y1, float* bn1,
    const float* g1w, const float* b1w, float* se1_in,
    const unsigned short* wp2, const float* c2b, const float* s1w1, const float* s1w2,
    float* y2, float* bn2,
    const float* g2w, const float* b2w, float* se2_in,
    const unsigned short* wp3, const float* c3b, const float* s2w1, const float* s2w2,
    float* y3, float* bn3,
    const float* g3w, const float* b3w, float* x2)
{
  __shared__ __align__(16) char sm[sizeof(ConvS)];
  const int bid = blockIdx.x;
  if(bid < 32){
    if(threadIdx.x >= 128){
      const int nb = nsteps + 1;
      #pragma nounroll
      for(int i=0;i<nb;i++){ asm volatile("s_barrier" ::: "memory"); }
      return;
    }
    __builtin_amdgcn_s_setprio(1);
    lstm_seg_body(bid, ts, nsteps, sm, axT, kw1, kw2, kb2, hidden, cstate);
    return;
  }
  const int cb = bid - 32;
  switch(phase){
    case 0:  // conv1 (1024)
      conv_body(cb&15, (cb>>4)&1, cb>>5, sm, x, wp1, c1b,
                nullptr, nullptr, nullptr, 0, y1, bn1, F_, C1_, 8);
      break;
    case 1:  // bn_act1 (256)
      bn_act_body(cb>>3, cb&7, sm, y1, bn1, g1w, b1w, se1_in, C1_, 1);
      break;
    case 2:  // conv2 + inline SE1 (2048)
      conv_body(cb&15, (cb>>4)&3, cb>>6, sm, y1, wp2, c2b,
                se1_in, s1w1, s1w2, C1_/16, y2, bn2, C1_, C2_, 5);
      break;
    case 3:  // bn_act2 (256)
      bn_act_body(cb>>3, cb&7, sm, y2, bn2, g2w, b2w, se2_in, C2_, 1);
      break;
    case 4:  // conv3 + inline SE2 (1024); y3 aliases y1 (dead after phase 2)
      conv_body(cb&15, (cb>>4)&1, cb>>5, sm, y2, wp3, c3b,
                se2_in, s2w1, s2w2, C2_/16, y3, bn3, C2_, C3_, 3);
      break;
    default: // 5: bn3 (256, t-sums only)
      bn_act_body(cb>>3, cb&7, sm, y3, bn3, g3w, b3w, x2, C3_, 0);
      break;
  }
}

// D7: norm (4096)
__global__ __launch_bounds__(256) void norm_kernel(
    const float* hidden, unsigned short* hnhi, unsigned short* hnlo)
{
  norm_body(blockIdx.x, hidden, hnhi, hnlo);
}

// D8: s symmetric (512 blocks x <=9 tile-iters)
__global__ __launch_bounds__(256) void s_kernel(
    const unsigned short* hnhi, const unsigned short* hnlo, double* rowsum, double* psum)
{
  __shared__ __align__(16) char sm[sizeof(SS)];
  s_sym_body(blockIdx.x, sm, hnhi, hnlo, rowsum, psum);
}

// D9: tail -- cluster(b) -> head1(b) -> head2(b), one block per batch.
__global__ __launch_bounds__(256) void tail_kernel(
    const double* rowsum, const double* psum, const float* hidden, float* corr, int* cuts,
    const float* eps_z, const float* eps_cat,
    const float* mu_w, const float* mu_b, const float* std_w, const float* std_b,
    const float* muc_w, const float* muc_b, const float* stdc_w, const float* stdc_b,
    float* out_mu, float* out_std, float* out_muc, float* out_stdc, float* x1,
    const float* x2, const float* fcw, const float* fcb, float* outls)
{
  __shared__ __align__(16) char sm[sizeof(CS)];
  const int b = blockIdx.x, tid = threadIdx.x;
  cluster_body(b, sm, rowsum, psum, hidden, corr, cuts);
  __syncthreads();
  head1_body(b, sm, corr, hidden, eps_z, eps_cat, mu_w, mu_b, std_w, std_b,
             muc_w, muc_b, stdc_w, stdc_b, out_mu, out_std, out_muc, out_stdc, x1);
  __syncthreads();
  struct H2 { float xa[256]; float lg[NC_]; };
  H2* s2 = (H2*)sm;
  s2->xa[tid] = (tid<128) ? x1[b*128+tid] : x2[b*128+(tid-128)]*(1.f/(float)T_);
  __syncthreads();
  if(tid<NC_){
    float s = fcb[tid];
    for(int k=0;k<256;k++) s += s2->xa[k]*fcw[k*NC_+tid];
    s2->lg[tid]=s;
  }
  __syncthreads();
  if(tid==0){
    float mx=s2->lg[0];
    for(int q=1;q<NC_;q++) mx=fmaxf(mx,s2->lg[q]);
    float se=0;
    for(int q=0;q<NC_;q++) se += __expf(s2->lg[q]-mx);
    const float lse = logf(se)+mx;
    for(int q=0;q<NC_;q++) outls[b*NC_+q] = s2->lg[q]-lse;
  }
}

// ================================================================ launch
extern "C" void kernel_launch(void* const* d_in, const int* in_sizes, int n_in,
                              void* d_out, int out_size, void* d_ws, size_t ws_size,
                              hipStream_t stream) {
  (void)in_sizes; (void)n_in; (void)out_size; (void)ws_size;
  const float* x        = (const float*)d_in[0];
  const float* eps_z    = (const float*)d_in[1];
  const float* eps_cat  = (const float*)d_in[2];
  const float* kan_w1   = (const float*)d_in[3];
  const float* kan_b1   = (const float*)d_in[4];
  const float* kan_w2   = (const float*)d_in[5];
  const float* kan_b2   = (const float*)d_in[6];
  const float* conv1_w  = (const float*)d_in[7];
  const float* conv1_b  = (const float*)d_in[8];
  const float* conv2_w  = (const float*)d_in[9];
  const float* conv2_b  = (const float*)d_in[10];
  const float* conv3_w  = (const float*)d_in[11];
  const float* conv3_b  = (const float*)d_in[12];
  const float* bn1_g    = (const float*)d_in[13];
  const float* bn1_b    = (const float*)d_in[14];
  const float* bn2_g    = (const float*)d_in[15];
  const float* bn2_b    = (const float*)d_in[16];
  const float* bn3_g    = (const float*)d_in[17];
  const float* bn3_b    = (const float*)d_in[18];
  const float* se1_w1   = (const float*)d_in[19];
  const float* se1_w2   = (const float*)d_in[20];
  const float* se2_w1   = (const float*)d_in[21];
  const float* se2_w2   = (const float*)d_in[22];
  const float* fc_mu_w  = (const float*)d_in[23];
  const float* fc_mu_b  = (const float*)d_in[24];
  const float* fc_std_w = (const float*)d_in[25];
  const float* fc_std_b = (const float*)d_in[26];
  const float* fc_muc_w = (const float*)d_in[27];
  const float* fc_muc_b = (const float*)d_in[28];
  const float* fc_stdc_w= (const float*)d_in[29];
  const float* fc_stdc_b= (const float*)d_in[30];
  const float* fc_w     = (const float*)d_in[31];
  const float* fc_b     = (const float*)d_in[32];

  float* out = (float*)d_out;
  float* out_ls   = out;
  float* out_mu   = out + 320;
  float* out_std  = out + 320 + 4096;
  float* out_muc  = out + 320 + 2*4096;
  float* out_stdc = out + 320 + 3*4096;

  float* ws = (float*)d_ws;
  const size_t SZ_HID = (size_t)B_*T_*H_;
  const size_t SZ_Y1  = (size_t)B_*T_*C1_;
  const size_t SZ_Y2  = (size_t)B_*T_*C2_;
  float*  hidden = ws;                      // [b][t][H] — never aliased
  float*  y1     = hidden + SZ_HID;         // conv1 out; reused as y3 after conv2
  float*  y2     = y1 + SZ_Y1;
  double* rowsum = (double*)(y2 + SZ_Y2);
  double* psum   = rowsum + (size_t)B_*T_;
  float*  corr   = (float*)(psum + (size_t)B_*T_);
  float*  x1     = corr + (size_t)B_*H_;
  float*  bnbuf  = x1 + (size_t)B_*H_;      // zeroed region starts here
  float*  bn1    = bnbuf;
  float*  bn2    = bnbuf + 2*C1_;
  float*  bn3    = bnbuf + 2*C1_ + 2*C2_;
  float*  se1_in = bnbuf + 1024;
  float*  se2_in = se1_in + (size_t)B_*C1_;
  float*  x2     = se2_in + (size_t)B_*C2_;
  int*    cuts   = (int*)(x2 + (size_t)B_*C3_);
  float*  cstate = (float*)(cuts + B_);     // lstm c checkpoint [B][H]
  float*  axbuf  = cstate + (size_t)B_*H_;  // axT: B*16*T
  unsigned short* wp1 = (unsigned short*)(axbuf + (size_t)B_*16*T_);
  unsigned short* wp2 = wp1 + (size_t)C1_*F_*8;
  unsigned short* wp3 = wp2 + (size_t)C2_*C1_*5;
  unsigned short* hnhi = wp3 + (size_t)C3_*C2_*3;
  unsigned short* hnlo = hnhi + (size_t)B_*T_*H_;
  float*  y3     = y1;   // y1 dead after conv2 phase; conv3 reuses it

  // zero bn accumulators + se/x2 t-sum accumulators; zero rowsum/psum
  // (symmetric S accumulates via f64 atomics)
  hipMemsetAsync(bnbuf, 0, (size_t)(1024 + B_*C1_ + B_*C2_ + B_*C3_)*sizeof(float), stream);
  hipMemsetAsync(rowsum, 0, (size_t)2*B_*T_*sizeof(double), stream);

  // D0: prepack (1280) + ax (2048)
  mega0_kernel<<<3328, 256, 0, stream>>>(conv1_w, conv2_w, conv3_w, wp1, wp2, wp3,
                                         x, kan_w1, kan_b1, axbuf);

  // D1..D6: lstm segments + conv-branch phases (splits sized to phase work)
  #define SEG_ARGS axbuf, kan_w1, kan_w2, kan_b2, hidden, cstate, \
      x, wp1, conv1_b, y1, bn1, bn1_g, bn1_b, se1_in, \
      wp2, conv2_b, se1_w1, se1_w2, y2, bn2, bn2_g, bn2_b, se2_in, \
      wp3, conv3_b, se2_w1, se2_w2, y3, bn3, bn3_g, bn3_b, x2
  seg_kernel<<<32 + 1024, 256, 0, stream>>>(  0, 144, 0, SEG_ARGS);  // conv1
  seg_kernel<<<32 +  256, 256, 0, stream>>>(144,  64, 1, SEG_ARGS);  // bn_act1
  seg_kernel<<<32 + 2048, 256, 0, stream>>>(208, 384, 2, SEG_ARGS);  // conv2
  seg_kernel<<<32 +  256, 256, 0, stream>>>(592,  64, 3, SEG_ARGS);  // bn_act2
  seg_kernel<<<32 + 1024, 256, 0, stream>>>(656, 240, 4, SEG_ARGS);  // conv3
  seg_kernel<<<32 +  256, 256, 0, stream>>>(896, 128, 5, SEG_ARGS);  // bn3
  #undef SEG_ARGS

  // D7: norm (4096)
  norm_kernel<<<4096, 256, 0, stream>>>(hidden, hnhi, hnlo);
  // D8: s symmetric (512)
  s_kernel<<<512, 256, 0, stream>>>(hnhi, hnlo, rowsum, psum);
  // D9: tail (cluster+head1+head2, 32)
  tail_kernel<<<B_, 256, 0, stream>>>(rowsum, psum, hidden, corr, cuts,
      eps_z, eps_cat,
      fc_mu_w, fc_mu_b, fc_std_w, fc_std_b, fc_muc_w, fc_muc_b, fc_stdc_w, fc_stdc_b,
      out_mu, out_std, out_muc, out_stdc, x1,
      x2, fc_w, fc_b, out_ls);
}

// Round 11
// 726.143 us; speedup vs baseline: 1.1700x; 1.0651x over previous
//
#include <hip/hip_runtime.h>
#include <math.h>

#define B_ 32
#define T_ 1024
#define F_ 64
#define H_ 128
#define D_ 192
#define KH_ 16
#define C1_ 128
#define C2_ 256
#define C3_ 128
#define NC_ 10

typedef float v2f __attribute__((ext_vector_type(2)));
typedef float f32x4 __attribute__((ext_vector_type(4)));
typedef __bf16 bfrag __attribute__((ext_vector_type(8)));

__device__ __forceinline__ float sig_(float x){ return 1.f/(1.f+__expf(-x)); }
__device__ __forceinline__ float tanh_(float x){ return 1.f - 2.f/(__expf(2.f*x)+1.f); }
__device__ __forceinline__ float gelu_(float x){ return 0.5f*x*(1.f+erff(x*0.70710678118654752f)); }
__device__ __forceinline__ float softplus_(float x){ return fmaxf(x,0.f) + log1pf(__expf(-fabsf(x))); }

__device__ __forceinline__ unsigned bfpack(float a, float b){
  unsigned ua = __float_as_uint(a), ub = __float_as_uint(b);
  ua = ua + 0x7FFFu + ((ua>>16)&1u);
  ub = ub + 0x7FFFu + ((ub>>16)&1u);
  return (ua>>16) | (ub & 0xFFFF0000u);
}
__device__ __forceinline__ unsigned short bf1(float a){
  unsigned ua = __float_as_uint(a);
  ua = ua + 0x7FFFu + ((ua>>16)&1u);
  return (unsigned short)(ua>>16);
}
__device__ __forceinline__ float bf2f(unsigned short h){
  return __uint_as_float(((unsigned)h)<<16);
}

#define QPERM_XOR1(x) __int_as_float(__builtin_amdgcn_mov_dpp(__float_as_int(x), 0xB1, 0xF, 0xF, true))
#define QPERM_XOR2(x) __int_as_float(__builtin_amdgcn_mov_dpp(__float_as_int(x), 0x4E, 0xF, 0xF, true))

#define LDS_BARRIER() asm volatile("s_waitcnt lgkmcnt(0)\n\ts_barrier" ::: "memory")

// ================================================================ bodies

// ---- ax precompute (transposed out: axT[b][j][t])
__device__ __forceinline__ void ax_body(int blk, char* smemraw,
    const float* __restrict__ x, const float* __restrict__ w1, const float* __restrict__ b1,
    float* __restrict__ axT)
{
  struct AxS { float xs[16][68]; float w1s[64][16]; };
  AxS* sm = (AxS*)smemraw;
  const int bt0 = blk*16;
  const int tid = threadIdx.x;
  for(int i=tid;i<64*16;i+=256){ sm->w1s[i>>4][i&15] = w1[i]; }
  for(int i=tid;i<16*64;i+=256){ const int r=i>>6, d=i&63; sm->xs[r][d] = x[(size_t)(bt0+r)*64 + d]; }
  __syncthreads();
  const int r = tid>>4, j = tid&15;
  float s = b1[j];
  #pragma unroll
  for(int d=0; d<64; d++) s += sm->xs[r][d]*sm->w1s[d][j];
  const int bt = bt0 + r;
  axT[((size_t)(bt>>10)*16 + j)*1024 + (bt&1023)] = s;
}

// ---- weight prepack (bf16 MFMA B-fragment blocks, all 3 convs)
// blocks 0-255 cover wp1 exactly (e<65536); 256-1279 cover wp2+wp3.
__device__ __forceinline__ void prepack_body(int blk,
    const float* __restrict__ w1s, const float* __restrict__ w2s, const float* __restrict__ w3s,
    unsigned short* __restrict__ wp1, unsigned short* __restrict__ wp2, unsigned short* __restrict__ wp3)
{
  int e = blk*256 + threadIdx.x;
  if(e >= 65536+163840+98304) return;
  const float* w; unsigned short* wp; int Cout, Cin, Kw;
  if(e < 65536){ w=w1s; wp=wp1; Cout=C1_; Cin=F_;  Kw=8; }
  else if(e < 65536+163840){ e-=65536; w=w2s; wp=wp2; Cout=C2_; Cin=C1_; Kw=5; }
  else { e-=229376; w=w3s; wp=wp3; Cout=C3_; Cin=C2_; Kw=3; }
  const int co = e/(Cin*Kw);
  const int rem = e - co*(Cin*Kw);
  const int ci = rem/Kw, kw = rem - ci*Kw;
  const int off = (((ci>>5)*Kw + kw)*(Cout>>4) + (co>>4))*512 + ((co&15)*4 + ((ci>>3)&3))*8 + (ci&7);
  wp[off] = bf1(w[e]);
}

// ---- row norms for 8 rows starting at absolute rowbase; bf16 hi/lo split
__device__ __forceinline__ void norm8_body(size_t rowbase,
    const float* __restrict__ hidden,
    unsigned short* __restrict__ hnhi, unsigned short* __restrict__ hnlo)
{
  const size_t row = rowbase + (threadIdx.x>>5);
  const int l = threadIdx.x&31;
  const float* hr = hidden + row*H_;
  float s = 0.f;
  for(int k=l;k<H_;k+=32){ float v=hr[k]; s+=v*v; }
  #pragma unroll
  for(int m=16;m>=1;m>>=1) s += __shfl_xor(s, m, 64);
  const float inv = 1.f/fmaxf(sqrtf(s), 1e-8f);
  const float4 v = *(const float4*)&hr[l*4];
  const float f0=v.x*inv, f1=v.y*inv, f2=v.z*inv, f3=v.w*inv;
  const unsigned short h0=bf1(f0), h1=bf1(f1), h2=bf1(f2), h3=bf1(f3);
  uint2 phi; phi.x = (unsigned)h0 | ((unsigned)h1<<16); phi.y = (unsigned)h2 | ((unsigned)h3<<16);
  *(uint2*)&hnhi[row*H_ + l*4] = phi;
  const unsigned short g0=bf1(f0-bf2f(h0)), g1=bf1(f1-bf2f(h1)), g2=bf1(f2-bf2f(h2)), g3=bf1(f3-bf2f(h3));
  uint2 plo; plo.x = (unsigned)g0 | ((unsigned)g1<<16); plo.y = (unsigned)g2 | ((unsigned)g3<<16);
  *(uint2*)&hnlo[row*H_ + l*4] = plo;
}

// ---- per-(b,chunk) t-sums of hidden over 64-row chunks (for fast corr)
__device__ __forceinline__ void chunk_body(int b, int c, char* smemraw,
    const float* __restrict__ hidden, float* __restrict__ chunksum)
{
  float* red = (float*)smemraw;   // 128 floats
  const int tid = threadIdx.x, h = tid&127, half = tid>>7;
  const float* hb = hidden + ((size_t)b*T_ + c*64)*H_;
  float s = 0.f;
  for(int t=half; t<64; t+=2) s += hb[(size_t)t*H_ + h];
  if(half==1) red[h] = s;
  __syncthreads();
  if(half==0) chunksum[((size_t)b*16 + c)*H_ + h] = s + red[h];
}

// ---- S-Gram tile-list body (symmetry-halved, flat j-major index).
// Tile (i,j), i<=j, flat f = j(j+1)/2 + i. Stages B (col block j) once per
// j-run (lists are j-contiguous), restages A per tile. Off-diagonal tiles:
// row-sums -> rowsum[i-rows]; col-sums -> rowsum+psum[j-rows] (all gi<gj).
// Diagonal: full path. f64 atomic accumulation into zeroed buffers.
struct SS {
  unsigned short Ahi[64*136];
  unsigned short Alo[64*136];
  unsigned short Bhi[64*136];
  unsigned short Blo[64*136];
  double red[64][17];
};
__device__ __forceinline__ void s_list_body(int b, int f0, int cnt, char* smemraw,
    const unsigned short* __restrict__ hnhi, const unsigned short* __restrict__ hnlo,
    double* __restrict__ rowsum, double* __restrict__ psum)
{
  SS* sm = (SS*)smemraw;
  const int tid = threadIdx.x, l = tid & 63, wv = tid >> 6;
  const int m = l & 15, q = l >> 4;
  const int arow = (wv*16 + m)*136;
  double* red = &sm->red[0][0];
  int curj = -1;

  for(int f=f0; f<f0+cnt; f++){
    int j = (int)((sqrtf(8.f*(float)f + 1.f) - 1.f)*0.5f);
    while((j*(j+1))/2 > f) j--;
    while(((j+1)*(j+2))/2 <= f) j++;
    const int i = f - (j*(j+1))/2;
    const int i0 = i*64, j0 = j*64;

    __syncthreads();
    if(j != curj){
      curj = j;
      const uint4* ghi = (const uint4*)(hnhi + ((size_t)b*T_ + j0)*H_);
      const uint4* glo = (const uint4*)(hnlo + ((size_t)b*T_ + j0)*H_);
      for(int t2=tid; t2<64*16; t2+=256){
        const int r = t2>>4, c8 = t2&15;
        *(uint4*)&sm->Bhi[r*136 + c8*8] = ghi[r*16 + c8];
        *(uint4*)&sm->Blo[r*136 + c8*8] = glo[r*16 + c8];
      }
    }
    {
      const uint4* ghi = (const uint4*)(hnhi + ((size_t)b*T_ + i0)*H_);
      const uint4* glo = (const uint4*)(hnlo + ((size_t)b*T_ + i0)*H_);
      for(int t2=tid; t2<64*16; t2+=256){
        const int r = t2>>4, c8 = t2&15;
        *(uint4*)&sm->Ahi[r*136 + c8*8] = ghi[r*16 + c8];
        *(uint4*)&sm->Alo[r*136 + c8*8] = glo[r*16 + c8];
      }
    }
    __syncthreads();

    f32x4 acc[4];
    #pragma unroll
    for(int nt=0;nt<4;nt++) acc[nt] = (f32x4)(0.f);
    #pragma unroll
    for(int kc=0;kc<4;kc++){
      const bfrag Ah = *(const bfrag*)&sm->Ahi[arow + kc*32 + q*8];
      const bfrag Al = *(const bfrag*)&sm->Alo[arow + kc*32 + q*8];
      #pragma unroll
      for(int nt=0;nt<4;nt++){
        const int brow = (nt*16 + m)*136 + kc*32 + q*8;
        const bfrag Bh = *(const bfrag*)&sm->Bhi[brow];
        const bfrag Bl = *(const bfrag*)&sm->Blo[brow];
        acc[nt] = __builtin_amdgcn_mfma_f32_16x16x32_bf16(Ah, Bh, acc[nt], 0, 0, 0);
        acc[nt] = __builtin_amdgcn_mfma_f32_16x16x32_bf16(Al, Bh, acc[nt], 0, 0, 0);
        acc[nt] = __builtin_amdgcn_mfma_f32_16x16x32_bf16(Ah, Bl, acc[nt], 0, 0, 0);
      }
    }

    if(i0 == j0){
      double rs[4]={0,0,0,0}, ps[4]={0,0,0,0};
      #pragma unroll
      for(int nt=0;nt<4;nt++){
        const int gj = j0 + nt*16 + m;
        #pragma unroll
        for(int r=0;r<4;r++){
          const int gi = i0 + wv*16 + q*4 + r;
          if(gi == gj) continue;
          const float sv = __expf(-5.5f*(1.f - acc[nt][r]));
          rs[r] += (double)sv;
          if(gj < gi) ps[r] += (double)sv;
        }
      }
      #pragma unroll
      for(int r=0;r<4;r++){
        #pragma unroll
        for(int mk=1;mk<16;mk<<=1){
          rs[r] += __shfl_xor(rs[r], mk, 64);
          ps[r] += __shfl_xor(ps[r], mk, 64);
        }
      }
      if(m == 0){
        const size_t gbase = (size_t)b*T_ + i0 + wv*16 + q*4;
        #pragma unroll
        for(int r=0;r<4;r++){
          unsafeAtomicAdd(&rowsum[gbase + r], rs[r]);
          unsafeAtomicAdd(&psum[gbase + r], ps[r]);
        }
      }
    } else {
      double rs[4]={0,0,0,0}, cs[4]={0,0,0,0};
      #pragma unroll
      for(int nt=0;nt<4;nt++){
        double csn = 0.0;
        #pragma unroll
        for(int r=0;r<4;r++){
          const float sv = __expf(-5.5f*(1.f - acc[nt][r]));
          rs[r] += (double)sv;
          csn   += (double)sv;
        }
        cs[nt] = csn;
      }
      #pragma unroll
      for(int r=0;r<4;r++){
        #pragma unroll
        for(int mk=1;mk<16;mk<<=1) rs[r] += __shfl_xor(rs[r], mk, 64);
      }
      if(m == 0){
        const size_t gbase = (size_t)b*T_ + i0 + wv*16 + q*4;
        #pragma unroll
        for(int r=0;r<4;r++) unsafeAtomicAdd(&rowsum[gbase + r], rs[r]);
      }
      #pragma unroll
      for(int nt=0;nt<4;nt++){
        cs[nt] += __shfl_xor(cs[nt], 16, 64);
        cs[nt] += __shfl_xor(cs[nt], 32, 64);
      }
      if(q == 0){
        #pragma unroll
        for(int nt=0;nt<4;nt++) red[wv*64 + nt*16 + m] = cs[nt];
      }
      __syncthreads();
      if(tid < 64){
        const double v = red[tid] + red[64+tid] + red[128+tid] + red[192+tid];
        unsafeAtomicAdd(&rowsum[(size_t)b*T_ + j0 + tid], v);
        unsafeAtomicAdd(&psum[(size_t)b*T_ + j0 + tid], v);
      }
    }
  }
}

// ---- cluster: prefix+dist+argmax + CHUNKED corr (chunksum + <=63 partial)
struct CS {
  double sr[256]; double sp[256]; double bd[256]; double totR;
  float c2[2][128]; int bidx[256]; int cut;
};
__device__ __forceinline__ void cluster_body(int b, char* smemraw,
    const double* __restrict__ rowsum, const double* __restrict__ psum,
    const float* __restrict__ hidden, const float* __restrict__ chunksum,
    float* __restrict__ corr, int* __restrict__ cuts)
{
  CS* sm = (CS*)smemraw;
  const int tid = threadIdx.x;
  const double* r = rowsum + (size_t)b*T_;
  const double* p = psum + (size_t)b*T_;
  double r4[4], p4[4];
  #pragma unroll
  for(int q=0;q<4;q++){ r4[q]=r[tid*4+q]; p4[q]=p[tid*4+q]; }
  sm->sr[tid]=r4[0]+r4[1]+r4[2]+r4[3];
  sm->sp[tid]=p4[0]+p4[1]+p4[2]+p4[3];
  __syncthreads();
  if(tid==0){
    double ar=0, ap=0;
    for(int i=0;i<256;i++){ double tr=sm->sr[i], tp=sm->sp[i]; sm->sr[i]=ar; sm->sp[i]=ap; ar+=tr; ap+=tp; }
    sm->totR = ar;
  }
  __syncthreads();
  double cr = sm->sr[tid], cp = sm->sp[tid];
  const double full = sm->totR;
  double best = -1e308; int bi = 1;
  #pragma unroll
  for(int q=0;q<4;q++){
    cr += r4[q]; cp += p4[q];
    const int i = 4*tid + q + 1;
    if(i < T_){
      const double TL = 2.0*cp;
      const double TRv = cr - TL;
      const double BR = full - TL - 2.0*TRv;
      const double di = (double)i, dn = (double)(T_-i);
      const double dist = TL/(di*di) + BR/(dn*dn) - (2.0*TRv)/(di*dn);
      if(dist > best){ best=dist; bi=i; }
    }
  }
  sm->bd[tid]=best; sm->bidx[tid]=bi;
  __syncthreads();
  if(tid==0){
    double bb=-1e308; int ii=1;
    for(int q=0;q<256;q++){ if(sm->bd[q]>bb){ bb=sm->bd[q]; ii=sm->bidx[q]; } }
    sm->cut=ii; cuts[b]=ii;
  }
  __syncthreads();
  const int cut = sm->cut;
  const int h = tid&127, half = tid>>7;
  float s=0.f;
  if(half==0){
    const int cf = cut>>6;
    for(int c=0;c<cf;c++) s += chunksum[((size_t)b*16 + c)*H_ + h];
  } else {
    const float* hb = hidden + (size_t)b*T_*H_;
    for(int t=(cut & ~63); t<cut; t++) s += hb[(size_t)t*H_ + h];
  }
  sm->c2[half][h]=s;
  __syncthreads();
  if(tid<128) corr[b*H_+tid] = (sm->c2[0][tid]+sm->c2[1][tid])/(float)cut;
}

// ---- VAE head1 (first 128 threads work)
__device__ __forceinline__ void head1_body(int b, char* smemraw,
    const float* __restrict__ corr, const float* __restrict__ hidden,
    const float* __restrict__ eps_z, const float* __restrict__ eps_cat,
    const float* __restrict__ mu_w, const float* __restrict__ mu_b,
    const float* __restrict__ std_w, const float* __restrict__ std_b,
    const float* __restrict__ muc_w, const float* __restrict__ muc_b,
    const float* __restrict__ stdc_w, const float* __restrict__ stdc_b,
    float* __restrict__ out_mu, float* __restrict__ out_std,
    float* __restrict__ out_muc, float* __restrict__ out_stdc, float* __restrict__ x1)
{
  struct H1 { float cs[128]; float xz[256]; };
  H1* sm = (H1*)smemraw;
  const int h = threadIdx.x;
  if(h<128){
    sm->cs[h]=corr[b*H_+h];
    sm->xz[h]=hidden[((size_t)b*T_ + (T_-1))*H_ + h];
  }
  __syncthreads();
  if(h<128){
    float m=mu_b[h], sdv=std_b[h];
    for(int k=0;k<H_;k++){ const float cv=sm->cs[k]; m+=cv*mu_w[k*H_+h]; sdv+=cv*std_w[k*H_+h]; }
    const float stdv = softplus_(sdv);
    out_mu[b*H_+h]=m; out_std[b*H_+h]=stdv;
    sm->xz[128+h] = m + stdv*eps_z[b*H_+h];
  }
  __syncthreads();
  if(h<128){
    float mc=muc_b[h], sc=stdc_b[h];
    for(int k=0;k<256;k++){ const float v=sm->xz[k]; mc+=v*muc_w[k*H_+h]; sc+=v*stdc_w[k*H_+h]; }
    const float stdc = softplus_(sc);
    out_muc[b*H_+h]=mc; out_stdc[b*H_+h]=stdc;
    x1[b*H_+h]=mc + stdc*eps_cat[b*H_+h];
  }
}

// ---- causal conv via bf16 MFMA + fused BN partials + optional inline SE scale
struct ConvS {
  float sescale[256];
  float seh[16];
  unsigned short xs[72*40];   // bf16 staging; reused as float part[]/ms[]
};
__device__ __forceinline__ void conv_body(int bx, int by, int bz, char* smemraw,
    const float* __restrict__ in, const unsigned short* __restrict__ wp,
    const float* __restrict__ bias,
    const float* __restrict__ se_in, const float* __restrict__ se_w1,
    const float* __restrict__ se_w2, int seR,
    float* __restrict__ y, float* __restrict__ bnacc, int Cin, int Cout, int Kw)
{
  ConvS* sm = (ConvS*)smemraw;
  unsigned short* xs = sm->xs;
  const int b = bz, t0 = bx*64, co0 = by*64;
  const int tid = threadIdx.x, l = tid&63, wv = tid>>6;
  const int q = l>>4, m = l&15;
  const int TW = 64 + Kw - 1;
  const int abase = (wv*16 + m)*40 + q*8;
  const int boff = (m*4 + q)*8;
  const bool use_se = (se_in != nullptr);

  if(use_se){
    float* ms = (float*)xs;
    if(tid<Cin) ms[tid] = se_in[b*Cin+tid] * (1.f/(float)T_);
    __syncthreads();
    if(tid<seR){ float s=0.f; for(int k=0;k<Cin;k++) s += ms[k]*se_w1[k*seR+tid]; sm->seh[tid]=fmaxf(s,0.f); }
    __syncthreads();
    if(tid<Cin){ float s=0.f; for(int k=0;k<seR;k++) s += sm->seh[k]*se_w2[k*Cin+tid]; sm->sescale[tid]=sig_(s); }
  }

  f32x4 acc[4];
  #pragma unroll
  for(int nt=0;nt<4;nt++) acc[nt] = (f32x4)(0.f);

  const int nchunks = Cin >> 5;
  for(int cc=0; cc<nchunks; cc++){
    __syncthreads();
    for(int idx=tid; idx<TW*8; idx+=256){
      const int r = idx>>3, c4 = (idx&7)*4;
      const int tg = t0 - (Kw-1) + r;
      uint2 pk = make_uint2(0u, 0u);
      if(tg >= 0){
        float4 v = *(const float4*)&in[((size_t)b*T_ + tg)*Cin + cc*32 + c4];
        if(use_se){
          const float4 s4 = *(const float4*)&sm->sescale[cc*32 + c4];
          v.x*=s4.x; v.y*=s4.y; v.z*=s4.z; v.w*=s4.w;
        }
        pk.x = bfpack(v.x, v.y); pk.y = bfpack(v.z, v.w);
      }
      *(uint2*)&xs[r*40 + c4] = pk;
    }
    __syncthreads();
    for(int kw=0; kw<Kw; kw++){
      const bfrag Af = *(const bfrag*)&xs[abase + kw*40];
      #pragma unroll
      for(int nt=0; nt<4; nt++){
        const unsigned short* wpp = wp + ((size_t)((cc*Kw + kw)*(Cout>>4) + (by*4 + nt)))*512 + boff;
        const bfrag Bf = *(const bfrag*)wpp;
        acc[nt] = __builtin_amdgcn_mfma_f32_16x16x32_bf16(Af, Bf, acc[nt], 0, 0, 0);
      }
    }
  }
  __syncthreads();
  float* part = (float*)xs;
  const int t_base = t0 + wv*16 + q*4;
  #pragma unroll
  for(int nt=0; nt<4; nt++){
    const int co = co0 + nt*16 + m;
    const float bv = bias[co];
    float s1 = 0.f, s2 = 0.f;
    #pragma unroll
    for(int r=0;r<4;r++){
      const float v = acc[nt][r] + bv;
      y[((size_t)b*T_ + t_base + r)*Cout + co] = v;
      s1 += v; s2 += v*v;
    }
    s1 += __shfl_xor(s1, 16); s1 += __shfl_xor(s1, 32);
    s2 += __shfl_xor(s2, 16); s2 += __shfl_xor(s2, 32);
    if(q==0){ part[(wv*64 + nt*16 + m)*2+0] = s1; part[(wv*64 + nt*16 + m)*2+1] = s2; }
  }
  __syncthreads();
  if(tid < 64){
    float a1=0.f, a2=0.f;
    #pragma unroll
    for(int w2i=0; w2i<4; w2i++){ a1 += part[(w2i*64+tid)*2+0]; a2 += part[(w2i*64+tid)*2+1]; }
    atomicAdd(&bnacc[co0 + tid], a1);
    atomicAdd(&bnacc[Cout + co0 + tid], a2);
  }
}

// ---- BN + gelu (writes activated y) + per-(b,c) t-sum accum
__device__ __forceinline__ void bn_act_body(int b, int chunk, char* smemraw,
    float* __restrict__ y, const float* __restrict__ bnacc,
    const float* __restrict__ gw, const float* __restrict__ bw,
    float* __restrict__ mean_acc, int C, int write_y)
{
  const int t0 = chunk*128, tid = threadIdx.x;
  const int c = tid & (C-1), part = tid / C, np = 256 / C;
  const float cnt = (float)(B_*T_);
  const float mm = bnacc[c]/cnt;
  const float var = bnacc[C+c]/cnt - mm*mm;
  const float sc = gw[c]/sqrtf(var+1e-3f);
  const float sh = bw[c] - mm*sc;
  float s = 0.f;
  for(int t=t0+part; t<t0+128; t+=np){
    const size_t off = ((size_t)b*T_ + t)*C + c;
    float v = y[off];
    v = gelu_(v*sc + sh);
    if(write_y) y[off] = v;
    s += v;
  }
  float* rs = (float*)smemraw;
  if(np > 1){
    rs[tid]=s;
    __syncthreads();
    if(part==0) s += rs[tid+C];
  }
  if(part==0) atomicAdd(&mean_acc[b*C+c], s);
}

// ---- LSTM scan SEGMENT body (measured-450us 2-wave structure),
// steps [ts, ts+nsteps); c checkpointed, h restored from hidden[ts-1].
__device__ __forceinline__ void lstm_seg_body(int b, int ts, int nsteps, char* smemraw,
    const float* __restrict__ axT, const float* __restrict__ w1,
    const float* __restrict__ w2, const float* __restrict__ b2,
    float* __restrict__ hidden, float* __restrict__ cstate)
{
  float (*hs)[148] = (float(*)[148])smemraw;
  const int tid = threadIdx.x;   // 0..127 (workers only)
  const int l = tid & 63, wv = tid >> 6;
  const int j = l >> 2, g = l & 3;
  const int hi = wv*64 + l;

  v2f w1hv[16];
  #pragma unroll
  for(int q=0;q<16;q++){
    w1hv[q].x = w1[(64 + g*32 + 2*q)*KH_ + j];
    w1hv[q].y = w1[(64 + g*32 + 2*q + 1)*KH_ + j];
  }
  v2f w2if[16], w2go[16];
  #pragma unroll
  for(int k=0;k<16;k++){
    w2if[k].x = w2[k*512 + hi];       w2if[k].y = w2[k*512 + 128 + hi];
    w2go[k].x = w2[k*512 + 256 + hi]; w2go[k].y = w2[k*512 + 384 + hi];
  }
  v2f bif, bgo;
  bif.x = b2[hi]; bif.y = b2[128+hi]; bgo.x = b2[256+hi]; bgo.y = b2[384+hi];

  const float* axr = axT + ((size_t)b*16 + j)*1024;
  float* hb = hidden + (size_t)b*T_*H_;
  const int hwi = (hi>>5)*36 + (hi&31);
  float c;
  if(ts == 0){
    for(int i=tid;i<2*148;i+=128) ((float*)hs)[i]=0.f;
    c = 0.f;
  } else {
    c = cstate[b*H_ + hi];
    hs[0][hwi] = hb[(size_t)(ts-1)*H_ + hi];
  }
  float4 axA = *(const float4*)&axr[ts];
  float4 axB = *(const float4*)&axr[ts+4];
  __syncthreads();   // barrier #1

#define LSTM_STEP(tt, axv, RB) { \
    const float* hsr = hs[RB]; \
    float* hsw = hs[1-(RB)]; \
    v2f ap0=(v2f)(0.f), ap1=(v2f)(0.f), ap2=(v2f)(0.f), ap3=(v2f)(0.f); \
    { const float4 hv = *(const float4*)&hsr[g*36 + 0];  ap0 += ((v2f){hv.x,hv.y})*w1hv[0]  + ((v2f){hv.z,hv.w})*w1hv[1]; } \
    { const float4 hv = *(const float4*)&hsr[g*36 + 4];  ap1 += ((v2f){hv.x,hv.y})*w1hv[2]  + ((v2f){hv.z,hv.w})*w1hv[3]; } \
    { const float4 hv = *(const float4*)&hsr[g*36 + 8];  ap2 += ((v2f){hv.x,hv.y})*w1hv[4]  + ((v2f){hv.z,hv.w})*w1hv[5]; } \
    { const float4 hv = *(const float4*)&hsr[g*36 + 12]; ap3 += ((v2f){hv.x,hv.y})*w1hv[6]  + ((v2f){hv.z,hv.w})*w1hv[7]; } \
    { const float4 hv = *(const float4*)&hsr[g*36 + 16]; ap0 += ((v2f){hv.x,hv.y})*w1hv[8]  + ((v2f){hv.z,hv.w})*w1hv[9]; } \
    { const float4 hv = *(const float4*)&hsr[g*36 + 20]; ap1 += ((v2f){hv.x,hv.y})*w1hv[10] + ((v2f){hv.z,hv.w})*w1hv[11]; } \
    { const float4 hv = *(const float4*)&hsr[g*36 + 24]; ap2 += ((v2f){hv.x,hv.y})*w1hv[12] + ((v2f){hv.z,hv.w})*w1hv[13]; } \
    { const float4 hv = *(const float4*)&hsr[g*36 + 28]; ap3 += ((v2f){hv.x,hv.y})*w1hv[14] + ((v2f){hv.z,hv.w})*w1hv[15]; } \
    const v2f apt = (ap0+ap1)+(ap2+ap3); \
    float a = apt.x + apt.y; \
    a += QPERM_XOR1(a); \
    a += QPERM_XOR2(a); \
    a += (axv); \
    const float g1 = a * sig_(a); \
    v2f aIF = bif, aGO = bgo; \
    _Pragma("unroll") \
    for(int k=0;k<16;k++){ \
      const float gk = __int_as_float(__builtin_amdgcn_readlane(__float_as_int(g1), 4*k)); \
      v2f gk2; gk2.x=gk; gk2.y=gk; \
      aIF += gk2 * w2if[k]; \
      aGO += gk2 * w2go[k]; \
    } \
    const float si = sig_(aIF.x); \
    const float sf = sig_(aIF.y); \
    const float tg = tanh_(aGO.x); \
    const float so = sig_(aGO.y); \
    c = sf*c + si*tg; \
    const float h = so * tanh_(c); \
    hsw[hwi] = h; \
    hb[(size_t)(tt)*H_ + hi] = h; \
    LDS_BARRIER(); \
  }

  const int te = ts + nsteps;
  for(int t0=ts;t0<te;t0+=4){
    const int tl = (t0+8 < 1020) ? (t0+8) : 1020;
    const float4 axC = *(const float4*)&axr[tl];
    LSTM_STEP(t0+0, axA.x, 0)
    LSTM_STEP(t0+1, axA.y, 1)
    LSTM_STEP(t0+2, axA.z, 0)
    LSTM_STEP(t0+3, axA.w, 1)
    axA = axB; axB = axC;
  }
#undef LSTM_STEP
  if(te < T_) cstate[b*H_ + hi] = c;
}

// ================================================================ kernels

// D0: prepack-wp1 (256) + ax (2048); wp2/wp3 prepack moved into seg0 shadow
__global__ __launch_bounds__(256) void mega0_kernel(
    const float* c1w, const float* c2w, const float* c3w,
    unsigned short* wp1, unsigned short* wp2, unsigned short* wp3,
    const float* x, const float* kw1, const float* kb1, float* axT)
{
  __shared__ __align__(16) char sm[16*68*4 + 64*16*4];
  const int bid = blockIdx.x;
  if(bid < 256) prepack_body(bid, c1w, c2w, c3w, wp1, wp2, wp3);
  else ax_body(bid-256, sm, x, kw1, kb1, axT);
}

// Small-LDS segment kernel (7KB): lstm | conv/bn phase | xtra-prepack |
// norm | chunk. Used for seg0-seg4 and D7. Phase ordering across the
// conv branch comes from dispatch boundaries (R7 scheme).
__global__ __launch_bounds__(256) void seg_kernel(
    int ts, int nsteps, int phase, int nphase, int nxtra,
    int nr0, int nnorm, int c0, int nchunk,
    const float* axT, const float* kw1, const float* kw2, const float* kb2,
    float* hidden, float* cstate,
    const float* x, const unsigned short* wp1, const float* c1b, float* y1, float* bn1,
    const float* g1w, const float* b1w, float* se1_in,
    const unsigned short* wp2, const float* c2b, const float* s1w1, const float* s1w2,
    float* y2, float* bn2,
    const float* g2w, const float* b2w, float* se2_in,
    const unsigned short* wp3, const float* c3b, const float* s2w1, const float* s2w2,
    float* y3, float* bn3,
    const float* c1w, const float* c2w, const float* c3w,
    unsigned short* wp1o, unsigned short* wp2o, unsigned short* wp3o,
    unsigned short* hnhi, unsigned short* hnlo, float* chunksum)
{
  __shared__ __align__(16) char sm[sizeof(ConvS)];
  const int bid = blockIdx.x;
  if(bid < 32){
    if(nsteps == 0) return;
    if(threadIdx.x >= 128){
      const int nb = nsteps + 1;
      #pragma nounroll
      for(int i=0;i<nb;i++){ asm volatile("s_barrier" ::: "memory"); }
      return;
    }
    __builtin_amdgcn_s_setprio(1);
    lstm_seg_body(bid, ts, nsteps, sm, axT, kw1, kw2, kb2, hidden, cstate);
    return;
  }
  int cb = bid - 32;
  if(cb < nphase){
    switch(phase){
      case 0:
        conv_body(cb&15, (cb>>4)&1, cb>>5, sm, x, wp1, c1b,
                  nullptr, nullptr, nullptr, 0, y1, bn1, F_, C1_, 8);
        break;
      case 1:
        bn_act_body(cb>>3, cb&7, sm, y1, bn1, g1w, b1w, se1_in, C1_, 1);
        break;
      case 2:
        conv_body(cb&15, (cb>>4)&3, cb>>6, sm, y1, wp2, c2b,
                  se1_in, s1w1, s1w2, C1_/16, y2, bn2, C1_, C2_, 5);
        break;
      case 3:
        bn_act_body(cb>>3, cb&7, sm, y2, bn2, g2w, b2w, se2_in, C2_, 1);
        break;
      default: // 4: conv3
        conv_body(cb&15, (cb>>4)&1, cb>>5, sm, y2, wp3, c3b,
                  se2_in, s2w1, s2w2, C2_/16, y3, bn3, C2_, C3_, 3);
        break;
    }
    return;
  }
  cb -= nphase;
  if(cb < nxtra){ prepack_body(256 + cb, c1w, c2w, c3w, wp1o, wp2o, wp3o); return; }
  cb -= nxtra;
  if(cb < nnorm){
    const int b = cb & 31, tb = cb >> 5;
    norm8_body((size_t)b*T_ + nr0 + tb*8, hidden, hnhi, hnlo);
    return;
  }
  cb -= nnorm;
  if(cb < nchunk){
    const int b = cb & 31;
    chunk_body(b, c0 + (cb>>5), sm, hidden, chunksum);
  }
}

// Large-LDS segment kernel (78KB SS): lstm | bn3 | norm | chunk | s-tiles.
// Used for seg5 (rings 0-9 in the lstm shadow; all its block types tolerate
// 2-blocks/CU occupancy) and D8 (leftover j>=10 bundles). Kept separate from
// seg_kernel so conv dispatches keep small static LDS (occupancy!).
__global__ __launch_bounds__(256) void segS_kernel(
    int ts, int nsteps, int nbn3,
    int nr0, int nnorm, int c0, int nchunk,
    int smode, int sringlo, int nstile,
    const float* axT, const float* kw1, const float* kw2, const float* kb2,
    float* hidden, float* cstate,
    float* y3, const float* bn3, const float* g3w, const float* b3w, float* x2,
    unsigned short* hnhi, unsigned short* hnlo, float* chunksum,
    double* rowsum, double* psum)
{
  __shared__ __align__(16) char sm[sizeof(SS)];
  const int bid = blockIdx.x;
  if(bid < 32){
    if(nsteps == 0) return;
    if(threadIdx.x >= 128){
      const int nb = nsteps + 1;
      #pragma nounroll
      for(int i=0;i<nb;i++){ asm volatile("s_barrier" ::: "memory"); }
      return;
    }
    __builtin_amdgcn_s_setprio(1);
    lstm_seg_body(bid, ts, nsteps, sm, axT, kw1, kw2, kb2, hidden, cstate);
    return;
  }
  int cb = bid - 32;
  if(cb < nbn3){
    bn_act_body(cb>>3, cb&7, sm, y3, bn3, g3w, b3w, x2, C3_, 0);
    return;
  }
  cb -= nbn3;
  if(cb < nnorm){
    const int b = cb & 31, tb = cb >> 5;
    norm8_body((size_t)b*T_ + nr0 + tb*8, hidden, hnhi, hnlo);
    return;
  }
  cb -= nnorm;
  if(cb < nchunk){
    const int b = cb & 31;
    chunk_body(b, c0 + (cb>>5), sm, hidden, chunksum);
    return;
  }
  cb -= nchunk;
  if(cb < nstile){
    const int b = cb & 31, k = cb >> 5;
    int f0, cnt;
    if(smode == 1){           // rings sringlo..: ring m = tiles (0..m, m)
      const int m = sringlo + k;
      f0 = (m*(m+1))/2; cnt = m + 1;
    } else {                  // D8 bundles over f in [55,136): 9x7 + 3x6
      f0 = 55 + ((k<9) ? 7*k : 63 + 6*(k-9));
      cnt = (k<9) ? 7 : 6;
    }
    s_list_body(b, f0, cnt, sm, hnhi, hnlo, rowsum, psum);
  }
}

// D9: tail -- cluster(b) -> head1(b) -> head2(b), one block per batch.
__global__ __launch_bounds__(256) void tail_kernel(
    const double* rowsum, const double* psum, const float* hidden,
    const float* chunksum, float* corr, int* cuts,
    const float* eps_z, const float* eps_cat,
    const float* mu_w, const float* mu_b, const float* std_w, const float* std_b,
    const float* muc_w, const float* muc_b, const float* stdc_w, const float* stdc_b,
    float* out_mu, float* out_std, float* out_muc, float* out_stdc, float* x1,
    const float* x2, const float* fcw, const float* fcb, float* outls)
{
  __shared__ __align__(16) char sm[sizeof(CS)];
  const int b = blockIdx.x, tid = threadIdx.x;
  cluster_body(b, sm, rowsum, psum, hidden, chunksum, corr, cuts);
  __syncthreads();
  head1_body(b, sm, corr, hidden, eps_z, eps_cat, mu_w, mu_b, std_w, std_b,
             muc_w, muc_b, stdc_w, stdc_b, out_mu, out_std, out_muc, out_stdc, x1);
  __syncthreads();
  struct H2 { float xa[256]; float lg[NC_]; };
  H2* s2 = (H2*)sm;
  s2->xa[tid] = (tid<128) ? x1[b*128+tid] : x2[b*128+(tid-128)]*(1.f/(float)T_);
  __syncthreads();
  if(tid<NC_){
    float s = fcb[tid];
    for(int k=0;k<256;k++) s += s2->xa[k]*fcw[k*NC_+tid];
    s2->lg[tid]=s;
  }
  __syncthreads();
  if(tid==0){
    float mx=s2->lg[0];
    for(int q=1;q<NC_;q++) mx=fmaxf(mx,s2->lg[q]);
    float se=0;
    for(int q=0;q<NC_;q++) se += __expf(s2->lg[q]-mx);
    const float lse = logf(se)+mx;
    for(int q=0;q<NC_;q++) outls[b*NC_+q] = s2->lg[q]-lse;
  }
}

// ================================================================ launch
extern "C" void kernel_launch(void* const* d_in, const int* in_sizes, int n_in,
                              void* d_out, int out_size, void* d_ws, size_t ws_size,
                              hipStream_t stream) {
  (void)in_sizes; (void)n_in; (void)out_size; (void)ws_size;
  const float* x        = (const float*)d_in[0];
  const float* eps_z    = (const float*)d_in[1];
  const float* eps_cat  = (const float*)d_in[2];
  const float* kan_w1   = (const float*)d_in[3];
  const float* kan_b1   = (const float*)d_in[4];
  const float* kan_w2   = (const float*)d_in[5];
  const float* kan_b2   = (const float*)d_in[6];
  const float* conv1_w  = (const float*)d_in[7];
  const float* conv1_b  = (const float*)d_in[8];
  const float* conv2_w  = (const float*)d_in[9];
  const float* conv2_b  = (const float*)d_in[10];
  const float* conv3_w  = (const float*)d_in[11];
  const float* conv3_b  = (const float*)d_in[12];
  const float* bn1_g    = (const float*)d_in[13];
  const float* bn1_b    = (const float*)d_in[14];
  const float* bn2_g    = (const float*)d_in[15];
  const float* bn2_b    = (const float*)d_in[16];
  const float* bn3_g    = (const float*)d_in[17];
  const float* bn3_b    = (const float*)d_in[18];
  const float* se1_w1   = (const float*)d_in[19];
  const float* se1_w2   = (const float*)d_in[20];
  const float* se2_w1   = (const float*)d_in[21];
  const float* se2_w2   = (const float*)d_in[22];
  const float* fc_mu_w  = (const float*)d_in[23];
  const float* fc_mu_b  = (const float*)d_in[24];
  const float* fc_std_w = (const float*)d_in[25];
  const float* fc_std_b = (const float*)d_in[26];
  const float* fc_muc_w = (const float*)d_in[27];
  const float* fc_muc_b = (const float*)d_in[28];
  const float* fc_stdc_w= (const float*)d_in[29];
  const float* fc_stdc_b= (const float*)d_in[30];
  const float* fc_w     = (const float*)d_in[31];
  const float* fc_b     = (const float*)d_in[32];

  float* out = (float*)d_out;
  float* out_ls   = out;
  float* out_mu   = out + 320;
  float* out_std  = out + 320 + 4096;
  float* out_muc  = out + 320 + 2*4096;
  float* out_stdc = out + 320 + 3*4096;

  float* ws = (float*)d_ws;
  const size_t SZ_HID = (size_t)B_*T_*H_;
  const size_t SZ_Y1  = (size_t)B_*T_*C1_;
  const size_t SZ_Y2  = (size_t)B_*T_*C2_;
  float*  hidden = ws;                      // [b][t][H] — never aliased
  float*  y1     = hidden + SZ_HID;         // conv1 out; reused as y3 after conv2
  float*  y2     = y1 + SZ_Y1;
  double* rowsum = (double*)(y2 + SZ_Y2);
  double* psum   = rowsum + (size_t)B_*T_;
  float*  corr   = (float*)(psum + (size_t)B_*T_);
  float*  x1     = corr + (size_t)B_*H_;
  float*  bnbuf  = x1 + (size_t)B_*H_;      // zeroed region starts here
  float*  bn1    = bnbuf;
  float*  bn2    = bnbuf + 2*C1_;
  float*  bn3    = bnbuf + 2*C1_ + 2*C2_;
  float*  se1_in = bnbuf + 1024;
  float*  se2_in = se1_in + (size_t)B_*C1_;
  float*  x2     = se2_in + (size_t)B_*C2_;
  int*    cuts   = (int*)(x2 + (size_t)B_*C3_);
  float*  cstate = (float*)(cuts + B_);     // lstm c checkpoint [B][H]
  float*  chunksum = cstate + (size_t)B_*H_;  // [B][16][H]
  float*  axbuf  = chunksum + (size_t)B_*16*H_;  // axT: B*16*T
  unsigned short* wp1 = (unsigned short*)(axbuf + (size_t)B_*16*T_);
  unsigned short* wp2 = wp1 + (size_t)C1_*F_*8;
  unsigned short* wp3 = wp2 + (size_t)C2_*C1_*5;
  unsigned short* hnhi = wp3 + (size_t)C3_*C2_*3;
  unsigned short* hnlo = hnhi + (size_t)B_*T_*H_;
  float*  y3     = y1;   // y1 dead after conv2 phase; conv3 reuses it

  // zero bn accumulators + se/x2 t-sum accumulators; zero rowsum/psum
  hipMemsetAsync(bnbuf, 0, (size_t)(1024 + B_*C1_ + B_*C2_ + B_*C3_)*sizeof(float), stream);
  hipMemsetAsync(rowsum, 0, (size_t)2*B_*T_*sizeof(double), stream);

  // D0: prepack-wp1 (256) + ax (2048)
  mega0_kernel<<<2304, 256, 0, stream>>>(conv1_w, conv2_w, conv3_w, wp1, wp2, wp3,
                                         x, kan_w1, kan_b1, axbuf);

  #define SEG_ARGS axbuf, kan_w1, kan_w2, kan_b2, hidden, cstate, \
      x, wp1, conv1_b, y1, bn1, bn1_g, bn1_b, se1_in, \
      wp2, conv2_b, se1_w1, se1_w2, y2, bn2, bn2_g, bn2_b, se2_in, \
      wp3, conv3_b, se2_w1, se2_w2, y3, bn3, \
      conv1_w, conv2_w, conv3_w, wp1, wp2, wp3, \
      hnhi, hnlo, chunksum
  // D1 seg0: lstm[0,144) + conv1(1024) + xtra prepack wp2/wp3(1024)
  seg_kernel<<<32+1024+1024, 256, 0, stream>>>(  0,144, 0,1024,1024,   0,   0,  0,  0, SEG_ARGS);
  // D2 seg1: lstm[144,208) + bn_act1(256) + norm[0,144)(576)
  seg_kernel<<<32+256+576,   256, 0, stream>>>(144, 64, 1, 256,   0,   0, 576,  0,  0, SEG_ARGS);
  // D3 seg2: lstm[208,592) + conv2(2048) + norm[144,208)(256) + chunks0-2(96)
  seg_kernel<<<32+2048+256+96,256,0, stream>>>(208,384, 2,2048,   0, 144, 256,  0, 96, SEG_ARGS);
  // D4 seg3: lstm[592,656) + bn_act2(256) + norm[208,592)(1536) + chunks3-8(192)
  seg_kernel<<<32+256+1536+192,256,0,stream>>>(592, 64, 3, 256,   0, 208,1536,  3,192, SEG_ARGS);
  // D5 seg4: lstm[656,896) + conv3(1024) + norm[592,656)(256) + chunk9(32)
  seg_kernel<<<32+1024+256+32,256,0, stream>>>(656,240, 4,1024,   0, 592, 256,  9, 32, SEG_ARGS);
  #undef SEG_ARGS

  #define SEGS_ARGS axbuf, kan_w1, kan_w2, kan_b2, hidden, cstate, \
      y3, bn3, bn3_g, bn3_b, x2, hnhi, hnlo, chunksum, rowsum, psum
  // D6 seg5 (78KB): lstm[896,1024) + bn3(256) + norm[656,896)(960)
  //                 + chunks10-13(128) + s-rings 0-9 (320; rows<640 normed)
  segS_kernel<<<32+256+960+128+320, 256, 0, stream>>>(
      896, 128, 256, 656, 960, 10, 128, 1, 0, 320, SEGS_ARGS);
  // D7 (7KB): norm[896,1024)(512) + chunks14-15(64)
  {
    #define SEG_ARGS axbuf, kan_w1, kan_w2, kan_b2, hidden, cstate, \
        x, wp1, conv1_b, y1, bn1, bn1_g, bn1_b, se1_in, \
        wp2, conv2_b, se1_w1, se1_w2, y2, bn2, bn2_g, bn2_b, se2_in, \
        wp3, conv3_b, se2_w1, se2_w2, y3, bn3, \
        conv1_w, conv2_w, conv3_w, wp1, wp2, wp3, \
        hnhi, hnlo, chunksum
    seg_kernel<<<32+512+64, 256, 0, stream>>>(0, 0, -1, 0, 0, 896, 512, 14, 64, SEG_ARGS);
    #undef SEG_ARGS
  }
  // D8 (78KB): leftover s tiles j>=10 (f in [55,136)), 12 bundles x32
  segS_kernel<<<32+384, 256, 0, stream>>>(
      0, 0, 0, 0, 0, 0, 0, 2, 0, 384, SEGS_ARGS);
  #undef SEGS_ARGS

  // D9: tail (cluster+head1+head2, 32)
  tail_kernel<<<B_, 256, 0, stream>>>(rowsum, psum, hidden, chunksum, corr, cuts,
      eps_z, eps_cat,
      fc_mu_w, fc_mu_b, fc_std_w, fc_std_b, fc_muc_w, fc_muc_b, fc_stdc_w, fc_stdc_b,
      out_mu, out_std, out_muc, out_stdc, x1,
      x2, fc_w, fc_b, out_ls);
}